// Round 1
// baseline (1846.562 us; speedup 1.0000x reference)
//
#include <hip/hip_runtime.h>
#include <math.h>

#define NND 50000
#define NED 800000
#define ETOT 850000   // edges + self-loops
#define NG 256
#define FEAT 128
#define CCH 256       // HEADS*HID
#define OUTD 128
#define NEG 0.2f

// ---------------- CSR build ----------------

__global__ void zero_int_kernel(int* p, int n) {
    int i = blockIdx.x * 256 + threadIdx.x;
    if (i < n) p[i] = 0;
}

__global__ void count_kernel(const int* __restrict__ ei, int* __restrict__ deg) {
    int e = blockIdx.x * 256 + threadIdx.x;
    if (e >= ETOT) return;
    int dst = (e < NED) ? ei[NED + e] : (e - NED);
    atomicAdd(&deg[dst], 1);
}

__global__ __launch_bounds__(256) void scan_kernel(const int* __restrict__ deg,
                                                   int* __restrict__ rowptr,
                                                   int* __restrict__ cursor) {
    __shared__ int tile[256];
    __shared__ int carry;
    if (threadIdx.x == 0) carry = 0;
    __syncthreads();
    for (int base = 0; base < NND; base += 256) {
        int i = base + threadIdx.x;
        int v = (i < NND) ? deg[i] : 0;
        tile[threadIdx.x] = v;
        __syncthreads();
        for (int off = 1; off < 256; off <<= 1) {
            int t = (threadIdx.x >= off) ? tile[threadIdx.x - off] : 0;
            __syncthreads();
            tile[threadIdx.x] += t;
            __syncthreads();
        }
        int excl = tile[threadIdx.x] - v;
        if (i < NND) { rowptr[i] = carry + excl; cursor[i] = carry + excl; }
        __syncthreads();
        if (threadIdx.x == 255) carry += tile[255];
        __syncthreads();
    }
    if (threadIdx.x == 0) rowptr[NND] = carry;
}

__global__ void scatter_kernel(const int* __restrict__ ei, int* __restrict__ cursor,
                               int* __restrict__ csrsrc) {
    int e = blockIdx.x * 256 + threadIdx.x;
    if (e >= ETOT) return;
    int s, d;
    if (e < NED) { s = ei[e]; d = ei[NED + e]; } else { s = d = e - NED; }
    int pos = atomicAdd(&cursor[d], 1);
    csrsrc[pos] = s;
}

// ---------------- GEMM: C[M,256] = A[M,K] @ B[K,256] ----------------

__global__ __launch_bounds__(256) void gemm_kernel(const float* __restrict__ A,
                                                   const float* __restrict__ B,
                                                   float* __restrict__ Cm,
                                                   int M, int K) {
    __shared__ float Asm[64][17];
    __shared__ float Bsm[16][65];
    const int t = threadIdx.x;
    const int tx = t & 15, ty = t >> 4;
    const int bn = blockIdx.x * 64, bm = blockIdx.y * 64;
    float acc[4][4] = {};
    for (int k0 = 0; k0 < K; k0 += 16) {
        for (int r = 0; r < 4; r++) {
            int lin = r * 256 + t;
            int m = lin >> 4, kk = lin & 15;
            int gm = bm + m;
            Asm[m][kk] = (gm < M) ? A[(size_t)gm * K + k0 + kk] : 0.f;
        }
        for (int r = 0; r < 4; r++) {
            int lin = r * 256 + t;
            int kk = lin >> 6, n = lin & 63;
            Bsm[kk][n] = B[(size_t)(k0 + kk) * CCH + bn + n];
        }
        __syncthreads();
        for (int kk = 0; kk < 16; kk++) {
            float a[4], b[4];
            for (int i = 0; i < 4; i++) a[i] = Asm[ty * 4 + i][kk];
            for (int j = 0; j < 4; j++) b[j] = Bsm[kk][tx * 4 + j];
            for (int i = 0; i < 4; i++)
                for (int j = 0; j < 4; j++) acc[i][j] += a[i] * b[j];
        }
        __syncthreads();
    }
    for (int i = 0; i < 4; i++) {
        int gm = bm + ty * 4 + i;
        if (gm >= M) continue;
        for (int j = 0; j < 4; j++)
            Cm[(size_t)gm * CCH + bn + tx * 4 + j] = acc[i][j];
    }
}

// ---------------- attention logits: alpha_src/dst [N,4] ----------------

__global__ __launch_bounds__(256) void alpha_kernel(const float* __restrict__ H,
                                                    const float* __restrict__ as_,
                                                    const float* __restrict__ ad_,
                                                    float* __restrict__ asrc,
                                                    float* __restrict__ adst) {
    int n = blockIdx.x, t = threadIdx.x;
    float h = H[(size_t)n * CCH + t];
    float ps = h * as_[t];
    float pd = h * ad_[t];
    for (int off = 32; off > 0; off >>= 1) {
        ps += __shfl_down(ps, off, 64);
        pd += __shfl_down(pd, off, 64);
    }
    if ((t & 63) == 0) {
        int hd = t >> 6;
        asrc[n * 4 + hd] = ps;
        adst[n * 4 + hd] = pd;
    }
}

// ---------------- per-dst softmax + aggregation + bias + ELU ----------------

__global__ __launch_bounds__(256) void agg_kernel(const float* __restrict__ H,
                                                  const float* __restrict__ asrc,
                                                  const float* __restrict__ adst,
                                                  const int* __restrict__ rowptr,
                                                  const int* __restrict__ csrsrc,
                                                  const float* __restrict__ bias,
                                                  float* __restrict__ Xo) {
    int n = blockIdx.x, t = threadIdx.x, hd = t >> 6;
    int rs = rowptr[n], re = rowptr[n + 1];
    float adv = adst[n * 4 + hd];
    float m = -1e30f;
    for (int e = rs; e < re; e++) {
        int s = csrsrc[e];
        float ev = asrc[s * 4 + hd] + adv;
        ev = ev > 0.f ? ev : NEG * ev;
        m = fmaxf(m, ev);
    }
    float ssum = 0.f, acc = 0.f;
    for (int e = rs; e < re; e++) {
        int s = csrsrc[e];
        float ev = asrc[s * 4 + hd] + adv;
        ev = ev > 0.f ? ev : NEG * ev;
        float w = expf(ev - m);
        ssum += w;
        acc += w * H[(size_t)s * CCH + t];
    }
    float o = acc / ssum + bias[t];
    Xo[(size_t)n * CCH + t] = o > 0.f ? o : expm1f(o);
}

// ---------------- pooling ----------------

__global__ void bounds_kernel(const int* __restrict__ batch, int* __restrict__ gstart) {
    int i = blockIdx.x * 256 + threadIdx.x;
    if (i >= NND) return;
    int b = batch[i];
    int bp = (i == 0) ? -1 : batch[i - 1];
    for (int g = bp + 1; g <= b; ++g) gstart[g] = i;
    if (i == NND - 1) {
        for (int g = b + 1; g <= NG; ++g) gstart[g] = NND;
    }
}

__global__ __launch_bounds__(256) void pool_kernel(const float* __restrict__ X,
                                                   const int* __restrict__ gstart,
                                                   float* __restrict__ gmean) {
    int g = blockIdx.x, t = threadIdx.x;
    int s = gstart[g], e = gstart[g + 1];
    float acc = 0.f;
    for (int i = s; i < e; i++) acc += X[(size_t)i * CCH + t];
    int cnt = e - s;
    gmean[g * CCH + t] = acc / (float)(cnt > 0 ? cnt : 1);
}

__global__ __launch_bounds__(128) void final_kernel(const float* __restrict__ gmean,
                                                    const float* __restrict__ Wf,
                                                    const float* __restrict__ bf,
                                                    float* __restrict__ out) {
    int g = blockIdx.x, c = threadIdx.x;
    const float* gv = gmean + g * CCH;
    float acc = bf[c];
    for (int k = 0; k < CCH; k++) acc += gv[k] * Wf[k * OUTD + c];
    __shared__ float red[128];
    red[c] = acc * acc;
    __syncthreads();
    for (int s = 64; s > 0; s >>= 1) {
        if (c < s) red[c] += red[c + s];
        __syncthreads();
    }
    float nrm = sqrtf(red[0]);
    out[g * OUTD + c] = acc / fmaxf(nrm, 1e-12f);
}

// ---------------- launch ----------------

extern "C" void kernel_launch(void* const* d_in, const int* in_sizes, int n_in,
                              void* d_out, int out_size, void* d_ws, size_t ws_size,
                              hipStream_t stream) {
    const float* x     = (const float*)d_in[0];
    const int*   ei    = (const int*)d_in[1];
    const int*   batch = (const int*)d_in[2];
    const float* W[3]  = {(const float*)d_in[3], (const float*)d_in[7],  (const float*)d_in[11]};
    const float* As[3] = {(const float*)d_in[4], (const float*)d_in[8],  (const float*)d_in[12]};
    const float* Ad[3] = {(const float*)d_in[5], (const float*)d_in[9],  (const float*)d_in[13]};
    const float* Bb[3] = {(const float*)d_in[6], (const float*)d_in[10], (const float*)d_in[14]};
    const float* Wf    = (const float*)d_in[15];
    const float* bf    = (const float*)d_in[16];
    float* out = (float*)d_out;

    // workspace layout
    float* bufH  = (float*)d_ws;                       // 50000*256
    float* bufX  = bufH + (size_t)NND * CCH;           // 50000*256
    float* asrc  = bufX + (size_t)NND * CCH;           // 50000*4
    float* adst  = asrc + (size_t)NND * 4;             // 50000*4
    float* gmean = adst + (size_t)NND * 4;             // 256*256
    int* deg     = (int*)(gmean + (size_t)NG * CCH);   // NND+1
    int* rowptr  = deg + (NND + 1);                    // NND+1
    int* cursor  = rowptr + (NND + 1);                 // NND+1
    int* csrsrc  = cursor + (NND + 1);                 // ETOT
    int* gstart  = csrsrc + ETOT;                      // NG+1

    // CSR build (dst-indexed, with self-loops)
    zero_int_kernel<<<(NND + 1 + 255) / 256, 256, 0, stream>>>(deg, NND + 1);
    count_kernel<<<(ETOT + 255) / 256, 256, 0, stream>>>(ei, deg);
    scan_kernel<<<1, 256, 0, stream>>>(deg, rowptr, cursor);
    scatter_kernel<<<(ETOT + 255) / 256, 256, 0, stream>>>(ei, cursor, csrsrc);
    bounds_kernel<<<(NND + 255) / 256, 256, 0, stream>>>(batch, gstart);

    // 3 GAT layers
    const float* xin = x;
    int K = FEAT;
    for (int l = 0; l < 3; l++) {
        dim3 g(CCH / 64, (NND + 63) / 64);
        gemm_kernel<<<g, 256, 0, stream>>>(xin, W[l], bufH, NND, K);
        alpha_kernel<<<NND, 256, 0, stream>>>(bufH, As[l], Ad[l], asrc, adst);
        agg_kernel<<<NND, 256, 0, stream>>>(bufH, asrc, adst, rowptr, csrsrc, Bb[l], bufX);
        xin = bufX;
        K = CCH;
    }

    // global mean pool + final linear + L2 normalize
    pool_kernel<<<NG, 256, 0, stream>>>(bufX, gstart, gmean);
    final_kernel<<<NG, 128, 0, stream>>>(gmean, Wf, bf, out);
}

// Round 2
// 1423.390 us; speedup vs baseline: 1.2973x; 1.2973x over previous
//
#include <hip/hip_runtime.h>
#include <math.h>

#define NND 50000
#define NED 800000
#define ETOT 850000   // edges + self-loops
#define NG 256
#define FEAT 128
#define CCH 256       // HEADS*HID
#define OUTD 128
#define NEG 0.2f

// ---------------- CSR build ----------------

__global__ void zero_int_kernel(int* p, int n) {
    int i = blockIdx.x * 256 + threadIdx.x;
    if (i < n) p[i] = 0;
}

__global__ void count_kernel(const int* __restrict__ ei, int* __restrict__ deg) {
    int e = blockIdx.x * 256 + threadIdx.x;
    if (e >= ETOT) return;
    int dst = (e < NED) ? ei[NED + e] : (e - NED);
    atomicAdd(&deg[dst], 1);
}

__global__ __launch_bounds__(256) void scan_kernel(const int* __restrict__ deg,
                                                   int* __restrict__ rowptr,
                                                   int* __restrict__ cursor) {
    __shared__ int tile[256];
    __shared__ int carry;
    if (threadIdx.x == 0) carry = 0;
    __syncthreads();
    for (int base = 0; base < NND; base += 256) {
        int i = base + threadIdx.x;
        int v = (i < NND) ? deg[i] : 0;
        tile[threadIdx.x] = v;
        __syncthreads();
        for (int off = 1; off < 256; off <<= 1) {
            int t = (threadIdx.x >= off) ? tile[threadIdx.x - off] : 0;
            __syncthreads();
            tile[threadIdx.x] += t;
            __syncthreads();
        }
        int excl = tile[threadIdx.x] - v;
        if (i < NND) { rowptr[i] = carry + excl; cursor[i] = carry + excl; }
        __syncthreads();
        if (threadIdx.x == 255) carry += tile[255];
        __syncthreads();
    }
    if (threadIdx.x == 0) rowptr[NND] = carry;
}

__global__ void scatter_kernel(const int* __restrict__ ei, int* __restrict__ cursor,
                               int* __restrict__ csrsrc) {
    int e = blockIdx.x * 256 + threadIdx.x;
    if (e >= ETOT) return;
    int s, d;
    if (e < NED) { s = ei[e]; d = ei[NED + e]; } else { s = d = e - NED; }
    int pos = atomicAdd(&cursor[d], 1);
    csrsrc[pos] = s;
}

// ---------------- GEMM: C[M,256] = A[M,K] @ B[K,256] ----------------

__global__ __launch_bounds__(256) void gemm_kernel(const float* __restrict__ A,
                                                   const float* __restrict__ B,
                                                   float* __restrict__ Cm,
                                                   int M, int K) {
    __shared__ float Asm[64][17];
    __shared__ float Bsm[16][65];
    const int t = threadIdx.x;
    const int tx = t & 15, ty = t >> 4;
    const int bn = blockIdx.x * 64, bm = blockIdx.y * 64;
    float acc[4][4] = {};
    for (int k0 = 0; k0 < K; k0 += 16) {
        for (int r = 0; r < 4; r++) {
            int lin = r * 256 + t;
            int m = lin >> 4, kk = lin & 15;
            int gm = bm + m;
            Asm[m][kk] = (gm < M) ? A[(size_t)gm * K + k0 + kk] : 0.f;
        }
        for (int r = 0; r < 4; r++) {
            int lin = r * 256 + t;
            int kk = lin >> 6, n = lin & 63;
            Bsm[kk][n] = B[(size_t)(k0 + kk) * CCH + bn + n];
        }
        __syncthreads();
        for (int kk = 0; kk < 16; kk++) {
            float a[4], b[4];
            for (int i = 0; i < 4; i++) a[i] = Asm[ty * 4 + i][kk];
            for (int j = 0; j < 4; j++) b[j] = Bsm[kk][tx * 4 + j];
            for (int i = 0; i < 4; i++)
                for (int j = 0; j < 4; j++) acc[i][j] += a[i] * b[j];
        }
        __syncthreads();
    }
    for (int i = 0; i < 4; i++) {
        int gm = bm + ty * 4 + i;
        if (gm >= M) continue;
        for (int j = 0; j < 4; j++)
            Cm[(size_t)gm * CCH + bn + tx * 4 + j] = acc[i][j];
    }
}

// ---------------- attention logits: alpha_src/dst [N,4] ----------------

__global__ __launch_bounds__(256) void alpha_kernel(const float* __restrict__ H,
                                                    const float* __restrict__ as_,
                                                    const float* __restrict__ ad_,
                                                    float* __restrict__ asrc,
                                                    float* __restrict__ adst) {
    int n = blockIdx.x, t = threadIdx.x;
    float h = H[(size_t)n * CCH + t];
    float ps = h * as_[t];
    float pd = h * ad_[t];
    for (int off = 32; off > 0; off >>= 1) {
        ps += __shfl_down(ps, off, 64);
        pd += __shfl_down(pd, off, 64);
    }
    if ((t & 63) == 0) {
        int hd = t >> 6;
        asrc[n * 4 + hd] = ps;
        adst[n * 4 + hd] = pd;
    }
}

// ---------------- softmax weights per (dst, head) ----------------
// w[e*4+h] = softmax over incident edges of leaky_relu(asrc[src]+adst[dst])

__global__ __launch_bounds__(256) void weight_kernel(const float* __restrict__ asrc,
                                                     const float* __restrict__ adst,
                                                     const int* __restrict__ rowptr,
                                                     const int* __restrict__ csrsrc,
                                                     float* __restrict__ w) {
    int i = blockIdx.x * 256 + threadIdx.x;   // over NND*4
    if (i >= NND * 4) return;
    int n = i >> 2, hd = i & 3;
    int rs = rowptr[n], re = rowptr[n + 1];
    float adv = adst[i];
    float m = -1e30f;
    for (int e = rs; e < re; e++) {
        int s = csrsrc[e];
        float ev = asrc[s * 4 + hd] + adv;
        ev = ev > 0.f ? ev : NEG * ev;
        w[e * 4 + hd] = ev;
        m = fmaxf(m, ev);
    }
    float ssum = 0.f;
    for (int e = rs; e < re; e++) {
        float v = __expf(w[e * 4 + hd] - m);
        w[e * 4 + hd] = v;
        ssum += v;
    }
    float inv = 1.f / ssum;
    for (int e = rs; e < re; e++) w[e * 4 + hd] *= inv;
}

// ---------------- weighted gather + bias + ELU ----------------
// One wave per dst node; lane owns 4 channels (float4).

__global__ __launch_bounds__(256) void agg_kernel(const float4* __restrict__ H4,
                                                  const float* __restrict__ w,
                                                  const int* __restrict__ rowptr,
                                                  const int* __restrict__ csrsrc,
                                                  const float4* __restrict__ bias4,
                                                  float4* __restrict__ Xo4) {
    int wave = threadIdx.x >> 6, lane = threadIdx.x & 63;
    int n = blockIdx.x * 4 + wave;
    if (n >= NND) return;
    int rs = rowptr[n], re = rowptr[n + 1];
    int hd = lane >> 4;   // channels 4*lane..4*lane+3 -> head (4*lane)>>6
    float4 acc = make_float4(0.f, 0.f, 0.f, 0.f);
    for (int e = rs; e < re; e++) {
        int s = csrsrc[e];
        float ww = w[e * 4 + hd];
        float4 hv = H4[(size_t)s * 64 + lane];
        acc.x += ww * hv.x;
        acc.y += ww * hv.y;
        acc.z += ww * hv.z;
        acc.w += ww * hv.w;
    }
    float4 bv = bias4[lane];
    float4 o;
    o.x = acc.x + bv.x; o.y = acc.y + bv.y; o.z = acc.z + bv.z; o.w = acc.w + bv.w;
    o.x = o.x > 0.f ? o.x : expm1f(o.x);
    o.y = o.y > 0.f ? o.y : expm1f(o.y);
    o.z = o.z > 0.f ? o.z : expm1f(o.z);
    o.w = o.w > 0.f ? o.w : expm1f(o.w);
    Xo4[(size_t)n * 64 + lane] = o;
}

// ---------------- pooling ----------------

__global__ void bounds_kernel(const int* __restrict__ batch, int* __restrict__ gstart) {
    int i = blockIdx.x * 256 + threadIdx.x;
    if (i >= NND) return;
    int b = batch[i];
    int bp = (i == 0) ? -1 : batch[i - 1];
    for (int g = bp + 1; g <= b; ++g) gstart[g] = i;
    if (i == NND - 1) {
        for (int g = b + 1; g <= NG; ++g) gstart[g] = NND;
    }
}

__global__ __launch_bounds__(256) void pool_kernel(const float* __restrict__ X,
                                                   const int* __restrict__ gstart,
                                                   float* __restrict__ gmean) {
    int g = blockIdx.x, t = threadIdx.x;
    int s = gstart[g], e = gstart[g + 1];
    float acc = 0.f;
    for (int i = s; i < e; i++) acc += X[(size_t)i * CCH + t];
    int cnt = e - s;
    gmean[g * CCH + t] = acc / (float)(cnt > 0 ? cnt : 1);
}

__global__ __launch_bounds__(128) void final_kernel(const float* __restrict__ gmean,
                                                    const float* __restrict__ Wf,
                                                    const float* __restrict__ bf,
                                                    float* __restrict__ out) {
    int g = blockIdx.x, c = threadIdx.x;
    const float* gv = gmean + g * CCH;
    float acc = bf[c];
    for (int k = 0; k < CCH; k++) acc += gv[k] * Wf[k * OUTD + c];
    __shared__ float red[128];
    red[c] = acc * acc;
    __syncthreads();
    for (int s = 64; s > 0; s >>= 1) {
        if (c < s) red[c] += red[c + s];
        __syncthreads();
    }
    float nrm = sqrtf(red[0]);
    out[g * OUTD + c] = acc / fmaxf(nrm, 1e-12f);
}

// ---------------- launch ----------------

extern "C" void kernel_launch(void* const* d_in, const int* in_sizes, int n_in,
                              void* d_out, int out_size, void* d_ws, size_t ws_size,
                              hipStream_t stream) {
    const float* x     = (const float*)d_in[0];
    const int*   ei    = (const int*)d_in[1];
    const int*   batch = (const int*)d_in[2];
    const float* W[3]  = {(const float*)d_in[3], (const float*)d_in[7],  (const float*)d_in[11]};
    const float* As[3] = {(const float*)d_in[4], (const float*)d_in[8],  (const float*)d_in[12]};
    const float* Ad[3] = {(const float*)d_in[5], (const float*)d_in[9],  (const float*)d_in[13]};
    const float* Bb[3] = {(const float*)d_in[6], (const float*)d_in[10], (const float*)d_in[14]};
    const float* Wf    = (const float*)d_in[15];
    const float* bf    = (const float*)d_in[16];
    float* out = (float*)d_out;

    // workspace layout
    float* bufH  = (float*)d_ws;                       // 50000*256
    float* bufX  = bufH + (size_t)NND * CCH;           // 50000*256
    float* asrc  = bufX + (size_t)NND * CCH;           // 50000*4
    float* adst  = asrc + (size_t)NND * 4;             // 50000*4
    float* wbuf  = adst + (size_t)NND * 4;             // ETOT*4
    float* gmean = wbuf + (size_t)ETOT * 4;            // 256*256
    int* deg     = (int*)(gmean + (size_t)NG * CCH);   // NND+1
    int* rowptr  = deg + (NND + 1);                    // NND+1
    int* cursor  = rowptr + (NND + 1);                 // NND+1
    int* csrsrc  = cursor + (NND + 1);                 // ETOT
    int* gstart  = csrsrc + ETOT;                      // NG+1

    // CSR build (dst-indexed, with self-loops)
    zero_int_kernel<<<(NND + 1 + 255) / 256, 256, 0, stream>>>(deg, NND + 1);
    count_kernel<<<(ETOT + 255) / 256, 256, 0, stream>>>(ei, deg);
    scan_kernel<<<1, 256, 0, stream>>>(deg, rowptr, cursor);
    scatter_kernel<<<(ETOT + 255) / 256, 256, 0, stream>>>(ei, cursor, csrsrc);
    bounds_kernel<<<(NND + 255) / 256, 256, 0, stream>>>(batch, gstart);

    // 3 GAT layers
    const float* xin = x;
    int K = FEAT;
    for (int l = 0; l < 3; l++) {
        dim3 g(CCH / 64, (NND + 63) / 64);
        gemm_kernel<<<g, 256, 0, stream>>>(xin, W[l], bufH, NND, K);
        alpha_kernel<<<NND, 256, 0, stream>>>(bufH, As[l], Ad[l], asrc, adst);
        weight_kernel<<<(NND * 4 + 255) / 256, 256, 0, stream>>>(asrc, adst, rowptr, csrsrc, wbuf);
        agg_kernel<<<(NND + 3) / 4, 256, 0, stream>>>((const float4*)bufH, wbuf, rowptr, csrsrc,
                                                      (const float4*)Bb[l], (float4*)bufX);
        xin = bufX;
        K = CCH;
    }

    // global mean pool + final linear + L2 normalize
    pool_kernel<<<NG, 256, 0, stream>>>(bufX, gstart, gmean);
    final_kernel<<<NG, 128, 0, stream>>>(gmean, Wf, bf, out);
}

// Round 3
// 1210.289 us; speedup vs baseline: 1.5257x; 1.1761x over previous
//
#include <hip/hip_runtime.h>
#include <math.h>

#define NND 50000
#define NED 800000
#define ETOT 850000   // edges + self-loops
#define NG 256
#define FEAT 128
#define CCH 256       // HEADS*HID
#define OUTD 128
#define NEG 0.2f
#define NBLK 196      // ceil(NND/256)

// ---------------- CSR build ----------------

__global__ void zero_int_kernel(int* p, int n) {
    int i = blockIdx.x * 256 + threadIdx.x;
    if (i < n) p[i] = 0;
}

__global__ void count_kernel(const int* __restrict__ ei, int* __restrict__ deg) {
    int e = blockIdx.x * 256 + threadIdx.x;
    if (e >= ETOT) return;
    int dst = (e < NED) ? ei[NED + e] : (e - NED);
    atomicAdd(&deg[dst], 1);
}

// stage 1: per-block sums of deg
__global__ __launch_bounds__(256) void scan_part_kernel(const int* __restrict__ deg,
                                                        int* __restrict__ bsum) {
    __shared__ int tile[256];
    int i = blockIdx.x * 256 + threadIdx.x;
    tile[threadIdx.x] = (i < NND) ? deg[i] : 0;
    __syncthreads();
    for (int s = 128; s > 0; s >>= 1) {
        if (threadIdx.x < s) tile[threadIdx.x] += tile[threadIdx.x + s];
        __syncthreads();
    }
    if (threadIdx.x == 0) bsum[blockIdx.x] = tile[0];
}

// stage 2: exclusive scan of the block sums (single small block)
__global__ __launch_bounds__(256) void scan_bsum_kernel(int* __restrict__ bsum,
                                                        int* __restrict__ boff,
                                                        int* __restrict__ total) {
    __shared__ int tile[256];
    int t = threadIdx.x;
    int v = (t < NBLK) ? bsum[t] : 0;
    tile[t] = v;
    __syncthreads();
    for (int off = 1; off < 256; off <<= 1) {
        int u = (t >= off) ? tile[t - off] : 0;
        __syncthreads();
        tile[t] += u;
        __syncthreads();
    }
    if (t < NBLK) boff[t] = tile[t] - v;
    if (t == 255) *total = tile[255];
}

// stage 3: block-local exclusive scan + block offset -> rowptr, cursor
__global__ __launch_bounds__(256) void scan_write_kernel(const int* __restrict__ deg,
                                                         const int* __restrict__ boff,
                                                         const int* __restrict__ total,
                                                         int* __restrict__ rowptr,
                                                         int* __restrict__ cursor) {
    __shared__ int tile[256];
    int i = blockIdx.x * 256 + threadIdx.x;
    int t = threadIdx.x;
    int v = (i < NND) ? deg[i] : 0;
    tile[t] = v;
    __syncthreads();
    for (int off = 1; off < 256; off <<= 1) {
        int u = (t >= off) ? tile[t - off] : 0;
        __syncthreads();
        tile[t] += u;
        __syncthreads();
    }
    if (i < NND) {
        int r = boff[blockIdx.x] + tile[t] - v;
        rowptr[i] = r;
        cursor[i] = r;
    }
    if (i == 0) rowptr[NND] = *total;
}

__global__ void scatter_kernel(const int* __restrict__ ei, int* __restrict__ cursor,
                               int* __restrict__ csrsrc) {
    int e = blockIdx.x * 256 + threadIdx.x;
    if (e >= ETOT) return;
    int s, d;
    if (e < NED) { s = ei[e]; d = ei[NED + e]; } else { s = d = e - NED; }
    int pos = atomicAdd(&cursor[d], 1);
    csrsrc[pos] = s;
}

// ---------------- GEMM: C[M,256] = A[M,K] @ B[K,256] ----------------

__global__ __launch_bounds__(256) void gemm_kernel(const float* __restrict__ A,
                                                   const float* __restrict__ B,
                                                   float* __restrict__ Cm,
                                                   int M, int K) {
    __shared__ float Asm[64][17];
    __shared__ float Bsm[16][65];
    const int t = threadIdx.x;
    const int tx = t & 15, ty = t >> 4;
    const int bn = blockIdx.x * 64, bm = blockIdx.y * 64;
    float acc[4][4] = {};
    for (int k0 = 0; k0 < K; k0 += 16) {
        for (int r = 0; r < 4; r++) {
            int lin = r * 256 + t;
            int m = lin >> 4, kk = lin & 15;
            int gm = bm + m;
            Asm[m][kk] = (gm < M) ? A[(size_t)gm * K + k0 + kk] : 0.f;
        }
        for (int r = 0; r < 4; r++) {
            int lin = r * 256 + t;
            int kk = lin >> 6, n = lin & 63;
            Bsm[kk][n] = B[(size_t)(k0 + kk) * CCH + bn + n];
        }
        __syncthreads();
        for (int kk = 0; kk < 16; kk++) {
            float a[4], b[4];
            for (int i = 0; i < 4; i++) a[i] = Asm[ty * 4 + i][kk];
            for (int j = 0; j < 4; j++) b[j] = Bsm[kk][tx * 4 + j];
            for (int i = 0; i < 4; i++)
                for (int j = 0; j < 4; j++) acc[i][j] += a[i] * b[j];
        }
        __syncthreads();
    }
    for (int i = 0; i < 4; i++) {
        int gm = bm + ty * 4 + i;
        if (gm >= M) continue;
        for (int j = 0; j < 4; j++)
            Cm[(size_t)gm * CCH + bn + tx * 4 + j] = acc[i][j];
    }
}

// ---------------- attention logits: alpha_src/dst [N,4] ----------------

__global__ __launch_bounds__(256) void alpha_kernel(const float* __restrict__ H,
                                                    const float* __restrict__ as_,
                                                    const float* __restrict__ ad_,
                                                    float* __restrict__ asrc,
                                                    float* __restrict__ adst) {
    int n = blockIdx.x, t = threadIdx.x;
    float h = H[(size_t)n * CCH + t];
    float ps = h * as_[t];
    float pd = h * ad_[t];
    for (int off = 32; off > 0; off >>= 1) {
        ps += __shfl_down(ps, off, 64);
        pd += __shfl_down(pd, off, 64);
    }
    if ((t & 63) == 0) {
        int hd = t >> 6;
        asrc[n * 4 + hd] = ps;
        adst[n * 4 + hd] = pd;
    }
}

// ---------------- softmax weights per (dst, head) ----------------

__global__ __launch_bounds__(256) void weight_kernel(const float* __restrict__ asrc,
                                                     const float* __restrict__ adst,
                                                     const int* __restrict__ rowptr,
                                                     const int* __restrict__ csrsrc,
                                                     float* __restrict__ w) {
    int i = blockIdx.x * 256 + threadIdx.x;   // over NND*4
    if (i >= NND * 4) return;
    int n = i >> 2, hd = i & 3;
    int rs = rowptr[n], re = rowptr[n + 1];
    float adv = adst[i];
    float m = -1e30f;
    for (int e = rs; e < re; e++) {
        int s = csrsrc[e];
        float ev = asrc[s * 4 + hd] + adv;
        ev = ev > 0.f ? ev : NEG * ev;
        w[e * 4 + hd] = ev;
        m = fmaxf(m, ev);
    }
    float ssum = 0.f;
    for (int e = rs; e < re; e++) {
        float v = __expf(w[e * 4 + hd] - m);
        w[e * 4 + hd] = v;
        ssum += v;
    }
    float inv = 1.f / ssum;
    for (int e = rs; e < re; e++) w[e * 4 + hd] *= inv;
}

// ---------------- weighted gather + bias + ELU ----------------

__global__ __launch_bounds__(256) void agg_kernel(const float4* __restrict__ H4,
                                                  const float* __restrict__ w,
                                                  const int* __restrict__ rowptr,
                                                  const int* __restrict__ csrsrc,
                                                  const float4* __restrict__ bias4,
                                                  float4* __restrict__ Xo4) {
    int wave = threadIdx.x >> 6, lane = threadIdx.x & 63;
    int n = blockIdx.x * 4 + wave;
    if (n >= NND) return;
    int rs = rowptr[n], re = rowptr[n + 1];
    int hd = lane >> 4;
    float4 acc = make_float4(0.f, 0.f, 0.f, 0.f);
    for (int e = rs; e < re; e++) {
        int s = csrsrc[e];
        float ww = w[e * 4 + hd];
        float4 hv = H4[(size_t)s * 64 + lane];
        acc.x += ww * hv.x;
        acc.y += ww * hv.y;
        acc.z += ww * hv.z;
        acc.w += ww * hv.w;
    }
    float4 bv = bias4[lane];
    float4 o;
    o.x = acc.x + bv.x; o.y = acc.y + bv.y; o.z = acc.z + bv.z; o.w = acc.w + bv.w;
    o.x = o.x > 0.f ? o.x : expm1f(o.x);
    o.y = o.y > 0.f ? o.y : expm1f(o.y);
    o.z = o.z > 0.f ? o.z : expm1f(o.z);
    o.w = o.w > 0.f ? o.w : expm1f(o.w);
    Xo4[(size_t)n * 64 + lane] = o;
}

// ---------------- pooling ----------------

__global__ void bounds_kernel(const int* __restrict__ batch, int* __restrict__ gstart) {
    int i = blockIdx.x * 256 + threadIdx.x;
    if (i >= NND) return;
    int b = batch[i];
    int bp = (i == 0) ? -1 : batch[i - 1];
    for (int g = bp + 1; g <= b; ++g) gstart[g] = i;
    if (i == NND - 1) {
        for (int g = b + 1; g <= NG; ++g) gstart[g] = NND;
    }
}

__global__ __launch_bounds__(256) void pool_kernel(const float* __restrict__ X,
                                                   const int* __restrict__ gstart,
                                                   float* __restrict__ gmean) {
    int g = blockIdx.x, t = threadIdx.x;
    int s = gstart[g], e = gstart[g + 1];
    float acc = 0.f;
    for (int i = s; i < e; i++) acc += X[(size_t)i * CCH + t];
    int cnt = e - s;
    gmean[g * CCH + t] = acc / (float)(cnt > 0 ? cnt : 1);
}

__global__ __launch_bounds__(128) void final_kernel(const float* __restrict__ gmean,
                                                    const float* __restrict__ Wf,
                                                    const float* __restrict__ bf,
                                                    float* __restrict__ out) {
    int g = blockIdx.x, c = threadIdx.x;
    const float* gv = gmean + g * CCH;
    float acc = bf[c];
    for (int k = 0; k < CCH; k++) acc += gv[k] * Wf[k * OUTD + c];
    __shared__ float red[128];
    red[c] = acc * acc;
    __syncthreads();
    for (int s = 64; s > 0; s >>= 1) {
        if (c < s) red[c] += red[c + s];
        __syncthreads();
    }
    float nrm = sqrtf(red[0]);
    out[g * OUTD + c] = acc / fmaxf(nrm, 1e-12f);
}

// ---------------- launch ----------------

extern "C" void kernel_launch(void* const* d_in, const int* in_sizes, int n_in,
                              void* d_out, int out_size, void* d_ws, size_t ws_size,
                              hipStream_t stream) {
    const float* x     = (const float*)d_in[0];
    const int*   ei    = (const int*)d_in[1];
    const int*   batch = (const int*)d_in[2];
    const float* W[3]  = {(const float*)d_in[3], (const float*)d_in[7],  (const float*)d_in[11]};
    const float* As[3] = {(const float*)d_in[4], (const float*)d_in[8],  (const float*)d_in[12]};
    const float* Ad[3] = {(const float*)d_in[5], (const float*)d_in[9],  (const float*)d_in[13]};
    const float* Bb[3] = {(const float*)d_in[6], (const float*)d_in[10], (const float*)d_in[14]};
    const float* Wf    = (const float*)d_in[15];
    const float* bf    = (const float*)d_in[16];
    float* out = (float*)d_out;

    // workspace layout
    float* bufH  = (float*)d_ws;                       // 50000*256
    float* bufX  = bufH + (size_t)NND * CCH;           // 50000*256
    float* asrc  = bufX + (size_t)NND * CCH;           // 50000*4
    float* adst  = asrc + (size_t)NND * 4;             // 50000*4
    float* wbuf  = adst + (size_t)NND * 4;             // ETOT*4
    float* gmean = wbuf + (size_t)ETOT * 4;            // 256*256
    int* deg     = (int*)(gmean + (size_t)NG * CCH);   // NND+1
    int* rowptr  = deg + (NND + 1);                    // NND+1
    int* cursor  = rowptr + (NND + 1);                 // NND+1
    int* csrsrc  = cursor + (NND + 1);                 // ETOT
    int* gstart  = csrsrc + ETOT;                      // NG+1
    int* bsum    = gstart + (NG + 1);                  // NBLK
    int* boff    = bsum + NBLK;                        // NBLK
    int* total   = boff + NBLK;                        // 1

    // CSR build (dst-indexed, with self-loops)
    zero_int_kernel<<<(NND + 1 + 255) / 256, 256, 0, stream>>>(deg, NND + 1);
    count_kernel<<<(ETOT + 255) / 256, 256, 0, stream>>>(ei, deg);
    scan_part_kernel<<<NBLK, 256, 0, stream>>>(deg, bsum);
    scan_bsum_kernel<<<1, 256, 0, stream>>>(bsum, boff, total);
    scan_write_kernel<<<NBLK, 256, 0, stream>>>(deg, boff, total, rowptr, cursor);
    scatter_kernel<<<(ETOT + 255) / 256, 256, 0, stream>>>(ei, cursor, csrsrc);
    bounds_kernel<<<(NND + 255) / 256, 256, 0, stream>>>(batch, gstart);

    // 3 GAT layers
    const float* xin = x;
    int K = FEAT;
    for (int l = 0; l < 3; l++) {
        dim3 g(CCH / 64, (NND + 63) / 64);
        gemm_kernel<<<g, 256, 0, stream>>>(xin, W[l], bufH, NND, K);
        alpha_kernel<<<NND, 256, 0, stream>>>(bufH, As[l], Ad[l], asrc, adst);
        weight_kernel<<<(NND * 4 + 255) / 256, 256, 0, stream>>>(asrc, adst, rowptr, csrsrc, wbuf);
        agg_kernel<<<(NND + 3) / 4, 256, 0, stream>>>((const float4*)bufH, wbuf, rowptr, csrsrc,
                                                      (const float4*)Bb[l], (float4*)bufX);
        xin = bufX;
        K = CCH;
    }

    // global mean pool + final linear + L2 normalize
    pool_kernel<<<NG, 256, 0, stream>>>(bufX, gstart, gmean);
    final_kernel<<<NG, 128, 0, stream>>>(gmean, Wf, bf, out);
}

// Round 4
// 919.755 us; speedup vs baseline: 2.0077x; 1.3159x over previous
//
#include <hip/hip_runtime.h>
#include <math.h>

#define NND 50000
#define NED 800000
#define ETOT 850000   // edges + self-loops
#define NG 256
#define FEAT 128
#define CCH 256       // HEADS*HID
#define OUTD 128
#define NEG 0.2f
#define NBLK 196      // ceil(NND/256)
#define M2 50048      // NND padded to 128

typedef __attribute__((ext_vector_type(8))) short short8;
typedef __attribute__((ext_vector_type(4))) float floatx4;

// ---------------- bf16 helpers ----------------

static __device__ inline unsigned short f2bf(float f) {
    union { float f; unsigned u; } v; v.f = f;
    unsigned r = v.u + 0x7FFF + ((v.u >> 16) & 1);   // RNE
    return (unsigned short)(r >> 16);
}
static __device__ inline float bf2f(unsigned short s) {
    union { unsigned u; float f; } v; v.u = ((unsigned)s) << 16;
    return v.f;
}

// ---------------- CSR build ----------------

__global__ void zero_int_kernel(int* p, int n) {
    int i = blockIdx.x * 256 + threadIdx.x;
    if (i < n) p[i] = 0;
}

__global__ void count_kernel(const int* __restrict__ ei, int* __restrict__ deg) {
    int e = blockIdx.x * 256 + threadIdx.x;
    if (e >= ETOT) return;
    int dst = (e < NED) ? ei[NED + e] : (e - NED);
    atomicAdd(&deg[dst], 1);
}

__global__ __launch_bounds__(256) void scan_part_kernel(const int* __restrict__ deg,
                                                        int* __restrict__ bsum) {
    __shared__ int tile[256];
    int i = blockIdx.x * 256 + threadIdx.x;
    tile[threadIdx.x] = (i < NND) ? deg[i] : 0;
    __syncthreads();
    for (int s = 128; s > 0; s >>= 1) {
        if (threadIdx.x < s) tile[threadIdx.x] += tile[threadIdx.x + s];
        __syncthreads();
    }
    if (threadIdx.x == 0) bsum[blockIdx.x] = tile[0];
}

__global__ __launch_bounds__(256) void scan_bsum_kernel(int* __restrict__ bsum,
                                                        int* __restrict__ boff,
                                                        int* __restrict__ total) {
    __shared__ int tile[256];
    int t = threadIdx.x;
    int v = (t < NBLK) ? bsum[t] : 0;
    tile[t] = v;
    __syncthreads();
    for (int off = 1; off < 256; off <<= 1) {
        int u = (t >= off) ? tile[t - off] : 0;
        __syncthreads();
        tile[t] += u;
        __syncthreads();
    }
    if (t < NBLK) boff[t] = tile[t] - v;
    if (t == 255) *total = tile[255];
}

__global__ __launch_bounds__(256) void scan_write_kernel(const int* __restrict__ deg,
                                                         const int* __restrict__ boff,
                                                         const int* __restrict__ total,
                                                         int* __restrict__ rowptr,
                                                         int* __restrict__ cursor) {
    __shared__ int tile[256];
    int i = blockIdx.x * 256 + threadIdx.x;
    int t = threadIdx.x;
    int v = (i < NND) ? deg[i] : 0;
    tile[t] = v;
    __syncthreads();
    for (int off = 1; off < 256; off <<= 1) {
        int u = (t >= off) ? tile[t - off] : 0;
        __syncthreads();
        tile[t] += u;
        __syncthreads();
    }
    if (i < NND) {
        int r = boff[blockIdx.x] + tile[t] - v;
        rowptr[i] = r;
        cursor[i] = r;
    }
    if (i == 0) rowptr[NND] = *total;
}

__global__ void scatter_kernel(const int* __restrict__ ei, int* __restrict__ cursor,
                               int* __restrict__ csrsrc) {
    int e = blockIdx.x * 256 + threadIdx.x;
    if (e >= ETOT) return;
    int s, d;
    if (e < NED) { s = ei[e]; d = ei[NED + e]; } else { s = d = e - NED; }
    int pos = atomicAdd(&cursor[d], 1);
    csrsrc[pos] = s;
}

// ---------------- decompose f32 -> bf16 hi/lo ----------------

// x [NND*128] f32 -> xh/xl same layout (vector of 4)
__global__ void decomp_x_kernel(const float4* __restrict__ x,
                                ushort4* __restrict__ xh, ushort4* __restrict__ xl) {
    int i = blockIdx.x * 256 + threadIdx.x;
    if (i >= NND * FEAT / 4) return;
    float4 v = x[i];
    ushort4 h, l;
    h.x = f2bf(v.x); l.x = f2bf(v.x - bf2f(h.x));
    h.y = f2bf(v.y); l.y = f2bf(v.y - bf2f(h.y));
    h.z = f2bf(v.z); l.z = f2bf(v.z - bf2f(h.z));
    h.w = f2bf(v.w); l.w = f2bf(v.w - bf2f(h.w));
    xh[i] = h; xl[i] = l;
}

// W [K x 256] f32 -> Wt hi/lo [256 x K] bf16 (transposed, n-major)
__global__ void wdecomp_kernel(const float* __restrict__ W,
                               unsigned short* __restrict__ wth,
                               unsigned short* __restrict__ wtl, int K) {
    int j = blockIdx.x * 256 + threadIdx.x;
    if (j >= 256 * K) return;
    int n = j / K, k = j - n * K;
    float v = W[k * 256 + n];
    unsigned short h = f2bf(v);
    wth[j] = h;
    wtl[j] = f2bf(v - bf2f(h));
}

// ---------------- MFMA GEMM: C[M2,256] = A[M2,K] @ Bt[256,K]^T ----------------
// hi/lo split precision: C = Ah*Bh + Ah*Bl + Al*Bh  (f32 accumulate)

#define BK 64
#define SK 72   // padded LDS row stride (shorts)

__global__ __launch_bounds__(256, 2) void gemm_mfma_kernel(
        const unsigned short* __restrict__ Ah, const unsigned short* __restrict__ Al,
        const unsigned short* __restrict__ Bh, const unsigned short* __restrict__ Bl,
        float* __restrict__ Cm, int K) {
    __shared__ unsigned short AsH[128 * SK], AsL[128 * SK];
    __shared__ unsigned short BsH[128 * SK], BsL[128 * SK];
    const int t = threadIdx.x;
    const int bn = blockIdx.x * 128;
    const int bm = blockIdx.y * 128;
    const int lane = t & 63, wv = t >> 6;
    const int wm = (wv >> 1) * 64, wn = (wv & 1) * 64;
    const int fr = lane & 15, q = lane >> 4;

    floatx4 acc[4][4] = {};

    const int lrow = t >> 3;          // 0..31
    const int lcol = (t & 7) * 8;     // 0..56

    for (int k0 = 0; k0 < K; k0 += BK) {
        // stage 128 rows x 64 k of each matrix
        for (int p = 0; p < 4; p++) {
            int row = p * 32 + lrow;
            size_t ga = (size_t)(bm + row) * K + k0 + lcol;
            size_t gb = (size_t)(bn + row) * K + k0 + lcol;
            *(short8*)&AsH[row * SK + lcol] = *(const short8*)&Ah[ga];
            *(short8*)&AsL[row * SK + lcol] = *(const short8*)&Al[ga];
            *(short8*)&BsH[row * SK + lcol] = *(const short8*)&Bh[gb];
            *(short8*)&BsL[row * SK + lcol] = *(const short8*)&Bl[gb];
        }
        __syncthreads();
        for (int kc = 0; kc < 2; kc++) {
            short8 ah[4], al[4], bh[4], bl[4];
            int ko = kc * 32 + q * 8;
            for (int mi = 0; mi < 4; mi++) {
                ah[mi] = *(const short8*)&AsH[(wm + mi * 16 + fr) * SK + ko];
                al[mi] = *(const short8*)&AsL[(wm + mi * 16 + fr) * SK + ko];
            }
            for (int ni = 0; ni < 4; ni++) {
                bh[ni] = *(const short8*)&BsH[(wn + ni * 16 + fr) * SK + ko];
                bl[ni] = *(const short8*)&BsL[(wn + ni * 16 + fr) * SK + ko];
            }
            for (int mi = 0; mi < 4; mi++)
                for (int ni = 0; ni < 4; ni++) {
                    acc[mi][ni] = __builtin_amdgcn_mfma_f32_16x16x32_bf16(
                        ah[mi], bh[ni], acc[mi][ni], 0, 0, 0);
                    acc[mi][ni] = __builtin_amdgcn_mfma_f32_16x16x32_bf16(
                        ah[mi], bl[ni], acc[mi][ni], 0, 0, 0);
                    acc[mi][ni] = __builtin_amdgcn_mfma_f32_16x16x32_bf16(
                        al[mi], bh[ni], acc[mi][ni], 0, 0, 0);
                }
        }
        __syncthreads();
    }
    // C/D layout: col = lane&15, row = (lane>>4)*4 + reg
    for (int mi = 0; mi < 4; mi++) {
        int row0 = bm + wm + mi * 16 + q * 4;
        for (int ni = 0; ni < 4; ni++) {
            int col = bn + wn + ni * 16 + fr;
            for (int r = 0; r < 4; r++)
                Cm[(size_t)(row0 + r) * CCH + col] = acc[mi][ni][r];
        }
    }
}

// ---------------- attention logits: alpha_src/dst [N,4] ----------------

__global__ __launch_bounds__(256) void alpha_kernel(const float* __restrict__ H,
                                                    const float* __restrict__ as_,
                                                    const float* __restrict__ ad_,
                                                    float* __restrict__ asrc,
                                                    float* __restrict__ adst) {
    int n = blockIdx.x, t = threadIdx.x;
    float h = H[(size_t)n * CCH + t];
    float ps = h * as_[t];
    float pd = h * ad_[t];
    for (int off = 32; off > 0; off >>= 1) {
        ps += __shfl_down(ps, off, 64);
        pd += __shfl_down(pd, off, 64);
    }
    if ((t & 63) == 0) {
        int hd = t >> 6;
        asrc[n * 4 + hd] = ps;
        adst[n * 4 + hd] = pd;
    }
}

// ---------------- softmax weights per (dst, head) ----------------

__global__ __launch_bounds__(256) void weight_kernel(const float* __restrict__ asrc,
                                                     const float* __restrict__ adst,
                                                     const int* __restrict__ rowptr,
                                                     const int* __restrict__ csrsrc,
                                                     float* __restrict__ w) {
    int i = blockIdx.x * 256 + threadIdx.x;   // over NND*4
    if (i >= NND * 4) return;
    int n = i >> 2, hd = i & 3;
    int rs = rowptr[n], re = rowptr[n + 1];
    float adv = adst[i];
    float m = -1e30f;
    for (int e = rs; e < re; e++) {
        int s = csrsrc[e];
        float ev = asrc[s * 4 + hd] + adv;
        ev = ev > 0.f ? ev : NEG * ev;
        w[e * 4 + hd] = ev;
        m = fmaxf(m, ev);
    }
    float ssum = 0.f;
    for (int e = rs; e < re; e++) {
        float v = __expf(w[e * 4 + hd] - m);
        w[e * 4 + hd] = v;
        ssum += v;
    }
    float inv = 1.f / ssum;
    for (int e = rs; e < re; e++) w[e * 4 + hd] *= inv;
}

// ---------------- weighted gather + bias + ELU -> bf16 hi/lo ----------------

__global__ __launch_bounds__(256) void agg_kernel(const float4* __restrict__ H4,
                                                  const float* __restrict__ w,
                                                  const int* __restrict__ rowptr,
                                                  const int* __restrict__ csrsrc,
                                                  const float4* __restrict__ bias4,
                                                  ushort4* __restrict__ xh4,
                                                  ushort4* __restrict__ xl4) {
    int wave = threadIdx.x >> 6, lane = threadIdx.x & 63;
    int n = blockIdx.x * 4 + wave;
    if (n >= NND) return;
    int rs = rowptr[n], re = rowptr[n + 1];
    int hd = lane >> 4;
    float4 acc = make_float4(0.f, 0.f, 0.f, 0.f);
    for (int e = rs; e < re; e++) {
        int s = csrsrc[e];
        float ww = w[e * 4 + hd];
        float4 hv = H4[(size_t)s * 64 + lane];
        acc.x += ww * hv.x;
        acc.y += ww * hv.y;
        acc.z += ww * hv.z;
        acc.w += ww * hv.w;
    }
    float4 bv = bias4[lane];
    float4 o;
    o.x = acc.x + bv.x; o.y = acc.y + bv.y; o.z = acc.z + bv.z; o.w = acc.w + bv.w;
    o.x = o.x > 0.f ? o.x : expm1f(o.x);
    o.y = o.y > 0.f ? o.y : expm1f(o.y);
    o.z = o.z > 0.f ? o.z : expm1f(o.z);
    o.w = o.w > 0.f ? o.w : expm1f(o.w);
    ushort4 h, l;
    h.x = f2bf(o.x); l.x = f2bf(o.x - bf2f(h.x));
    h.y = f2bf(o.y); l.y = f2bf(o.y - bf2f(h.y));
    h.z = f2bf(o.z); l.z = f2bf(o.z - bf2f(h.z));
    h.w = f2bf(o.w); l.w = f2bf(o.w - bf2f(h.w));
    xh4[(size_t)n * 64 + lane] = h;
    xl4[(size_t)n * 64 + lane] = l;
}

// ---------------- pooling ----------------

__global__ void bounds_kernel(const int* __restrict__ batch, int* __restrict__ gstart) {
    int i = blockIdx.x * 256 + threadIdx.x;
    if (i >= NND) return;
    int b = batch[i];
    int bp = (i == 0) ? -1 : batch[i - 1];
    for (int g = bp + 1; g <= b; ++g) gstart[g] = i;
    if (i == NND - 1) {
        for (int g = b + 1; g <= NG; ++g) gstart[g] = NND;
    }
}

__global__ __launch_bounds__(256) void pool_kernel(const unsigned short* __restrict__ xh,
                                                   const unsigned short* __restrict__ xl,
                                                   const int* __restrict__ gstart,
                                                   float* __restrict__ gmean) {
    int g = blockIdx.x, t = threadIdx.x;
    int s = gstart[g], e = gstart[g + 1];
    float acc = 0.f;
    for (int i = s; i < e; i++)
        acc += bf2f(xh[(size_t)i * CCH + t]) + bf2f(xl[(size_t)i * CCH + t]);
    int cnt = e - s;
    gmean[g * CCH + t] = acc / (float)(cnt > 0 ? cnt : 1);
}

__global__ __launch_bounds__(128) void final_kernel(const float* __restrict__ gmean,
                                                    const float* __restrict__ Wf,
                                                    const float* __restrict__ bf,
                                                    float* __restrict__ out) {
    int g = blockIdx.x, c = threadIdx.x;
    const float* gv = gmean + g * CCH;
    float acc = bf[c];
    for (int k = 0; k < CCH; k++) acc += gv[k] * Wf[k * OUTD + c];
    __shared__ float red[128];
    red[c] = acc * acc;
    __syncthreads();
    for (int s = 64; s > 0; s >>= 1) {
        if (c < s) red[c] += red[c + s];
        __syncthreads();
    }
    float nrm = sqrtf(red[0]);
    out[g * OUTD + c] = acc / fmaxf(nrm, 1e-12f);
}

// ---------------- launch ----------------

extern "C" void kernel_launch(void* const* d_in, const int* in_sizes, int n_in,
                              void* d_out, int out_size, void* d_ws, size_t ws_size,
                              hipStream_t stream) {
    const float* x     = (const float*)d_in[0];
    const int*   ei    = (const int*)d_in[1];
    const int*   batch = (const int*)d_in[2];
    const float* W[3]  = {(const float*)d_in[3], (const float*)d_in[7],  (const float*)d_in[11]};
    const float* As[3] = {(const float*)d_in[4], (const float*)d_in[8],  (const float*)d_in[12]};
    const float* Ad[3] = {(const float*)d_in[5], (const float*)d_in[9],  (const float*)d_in[13]};
    const float* Bb[3] = {(const float*)d_in[6], (const float*)d_in[10], (const float*)d_in[14]};
    const float* Wf    = (const float*)d_in[15];
    const float* bf    = (const float*)d_in[16];
    float* out = (float*)d_out;

    // workspace layout
    float* bufH = (float*)d_ws;                                   // M2*256 f32
    unsigned short* xh  = (unsigned short*)(bufH + (size_t)M2 * CCH);  // M2*256 bf16
    unsigned short* xl  = xh + (size_t)M2 * CCH;
    unsigned short* wth = xl + (size_t)M2 * CCH;                  // 256*256
    unsigned short* wtl = wth + 256 * 256;
    float* asrc  = (float*)(wtl + 256 * 256);                     // NND*4
    float* adst  = asrc + (size_t)NND * 4;
    float* wbuf  = adst + (size_t)NND * 4;                        // ETOT*4
    float* gmean = wbuf + (size_t)ETOT * 4;                       // NG*256
    int* deg     = (int*)(gmean + (size_t)NG * CCH);              // NND+1
    int* rowptr  = deg + (NND + 1);
    int* cursor  = rowptr + (NND + 1);
    int* csrsrc  = cursor + (NND + 1);                            // ETOT
    int* gstart  = csrsrc + ETOT;                                 // NG+1
    int* bsum    = gstart + (NG + 1);                             // NBLK
    int* boff    = bsum + NBLK;
    int* total   = boff + NBLK;

    // CSR build (dst-indexed, with self-loops)
    zero_int_kernel<<<(NND + 1 + 255) / 256, 256, 0, stream>>>(deg, NND + 1);
    count_kernel<<<(ETOT + 255) / 256, 256, 0, stream>>>(ei, deg);
    scan_part_kernel<<<NBLK, 256, 0, stream>>>(deg, bsum);
    scan_bsum_kernel<<<1, 256, 0, stream>>>(bsum, boff, total);
    scan_write_kernel<<<NBLK, 256, 0, stream>>>(deg, boff, total, rowptr, cursor);
    scatter_kernel<<<(ETOT + 255) / 256, 256, 0, stream>>>(ei, cursor, csrsrc);
    bounds_kernel<<<(NND + 255) / 256, 256, 0, stream>>>(batch, gstart);

    // decompose layer-0 activations
    decomp_x_kernel<<<(NND * FEAT / 4 + 255) / 256, 256, 0, stream>>>(
        (const float4*)x, (ushort4*)xh, (ushort4*)xl);

    // 3 GAT layers
    int K = FEAT;
    for (int l = 0; l < 3; l++) {
        wdecomp_kernel<<<K, 256, 0, stream>>>(W[l], wth, wtl, K);
        dim3 g(2, M2 / 128);
        gemm_mfma_kernel<<<g, 256, 0, stream>>>(xh, xl, wth, wtl, bufH, K);
        alpha_kernel<<<NND, 256, 0, stream>>>(bufH, As[l], Ad[l], asrc, adst);
        weight_kernel<<<(NND * 4 + 255) / 256, 256, 0, stream>>>(asrc, adst, rowptr, csrsrc, wbuf);
        agg_kernel<<<(NND + 3) / 4, 256, 0, stream>>>((const float4*)bufH, wbuf, rowptr, csrsrc,
                                                      (const float4*)Bb[l], (ushort4*)xh, (ushort4*)xl);
        K = CCH;
    }

    // global mean pool + final linear + L2 normalize
    pool_kernel<<<NG, 256, 0, stream>>>(xh, xl, gstart, gmean);
    final_kernel<<<NG, 128, 0, stream>>>(gmean, Wf, bf, out);
}

// Round 5
// 759.011 us; speedup vs baseline: 2.4329x; 1.2118x over previous
//
#include <hip/hip_runtime.h>
#include <math.h>

#define NND 50000
#define NED 800000
#define ETOT 850000   // edges + self-loops
#define NG 256
#define FEAT 128
#define CCH 256       // HEADS*HID
#define OUTD 128
#define NEG 0.2f
#define NBLK 196      // ceil(NND/256)
#define M2 50048      // NND padded to 128

typedef __attribute__((ext_vector_type(8))) short short8;
typedef __attribute__((ext_vector_type(4))) float floatx4;
typedef __attribute__((ext_vector_type(4))) _Float16 half4;

// ---------------- bf16 helpers ----------------

static __device__ inline unsigned short f2bf(float f) {
    union { float f; unsigned u; } v; v.f = f;
    unsigned r = v.u + 0x7FFF + ((v.u >> 16) & 1);   // RNE
    return (unsigned short)(r >> 16);
}
static __device__ inline float bf2f(unsigned short s) {
    union { unsigned u; float f; } v; v.u = ((unsigned)s) << 16;
    return v.f;
}

// ---------------- CSR build ----------------

__global__ void zero_int_kernel(int* p, int n) {
    int i = blockIdx.x * 256 + threadIdx.x;
    if (i < n) p[i] = 0;
}

__global__ void count_kernel(const int* __restrict__ ei, int* __restrict__ deg) {
    int e = blockIdx.x * 256 + threadIdx.x;
    if (e >= ETOT) return;
    int dst = (e < NED) ? ei[NED + e] : (e - NED);
    atomicAdd(&deg[dst], 1);
}

__global__ __launch_bounds__(256) void scan_part_kernel(const int* __restrict__ deg,
                                                        int* __restrict__ bsum) {
    __shared__ int tile[256];
    int i = blockIdx.x * 256 + threadIdx.x;
    tile[threadIdx.x] = (i < NND) ? deg[i] : 0;
    __syncthreads();
    for (int s = 128; s > 0; s >>= 1) {
        if (threadIdx.x < s) tile[threadIdx.x] += tile[threadIdx.x + s];
        __syncthreads();
    }
    if (threadIdx.x == 0) bsum[blockIdx.x] = tile[0];
}

__global__ __launch_bounds__(256) void scan_bsum_kernel(int* __restrict__ bsum,
                                                        int* __restrict__ boff,
                                                        int* __restrict__ total) {
    __shared__ int tile[256];
    int t = threadIdx.x;
    int v = (t < NBLK) ? bsum[t] : 0;
    tile[t] = v;
    __syncthreads();
    for (int off = 1; off < 256; off <<= 1) {
        int u = (t >= off) ? tile[t - off] : 0;
        __syncthreads();
        tile[t] += u;
        __syncthreads();
    }
    if (t < NBLK) boff[t] = tile[t] - v;
    if (t == 255) *total = tile[255];
}

__global__ __launch_bounds__(256) void scan_write_kernel(const int* __restrict__ deg,
                                                         const int* __restrict__ boff,
                                                         const int* __restrict__ total,
                                                         int* __restrict__ rowptr,
                                                         int* __restrict__ cursor) {
    __shared__ int tile[256];
    int i = blockIdx.x * 256 + threadIdx.x;
    int t = threadIdx.x;
    int v = (i < NND) ? deg[i] : 0;
    tile[t] = v;
    __syncthreads();
    for (int off = 1; off < 256; off <<= 1) {
        int u = (t >= off) ? tile[t - off] : 0;
        __syncthreads();
        tile[t] += u;
        __syncthreads();
    }
    if (i < NND) {
        int r = boff[blockIdx.x] + tile[t] - v;
        rowptr[i] = r;
        cursor[i] = r;
    }
    if (i == 0) rowptr[NND] = *total;
}

__global__ void scatter_kernel(const int* __restrict__ ei, int* __restrict__ cursor,
                               int* __restrict__ csrsrc) {
    int e = blockIdx.x * 256 + threadIdx.x;
    if (e >= ETOT) return;
    int s, d;
    if (e < NED) { s = ei[e]; d = ei[NED + e]; } else { s = d = e - NED; }
    int pos = atomicAdd(&cursor[d], 1);
    csrsrc[pos] = s;
}

// ---------------- decompose f32 -> bf16 hi/lo ----------------

__global__ void decomp_x_kernel(const float4* __restrict__ x,
                                ushort4* __restrict__ xh, ushort4* __restrict__ xl) {
    int i = blockIdx.x * 256 + threadIdx.x;
    if (i >= NND * FEAT / 4) return;
    float4 v = x[i];
    ushort4 h, l;
    h.x = f2bf(v.x); l.x = f2bf(v.x - bf2f(h.x));
    h.y = f2bf(v.y); l.y = f2bf(v.y - bf2f(h.y));
    h.z = f2bf(v.z); l.z = f2bf(v.z - bf2f(h.z));
    h.w = f2bf(v.w); l.w = f2bf(v.w - bf2f(h.w));
    xh[i] = h; xl[i] = l;
}

// W [K x 256] f32 -> Wt hi/lo [256 x K] bf16 (transposed, n-major)
__global__ void wdecomp_kernel(const float* __restrict__ W,
                               unsigned short* __restrict__ wth,
                               unsigned short* __restrict__ wtl, int K) {
    int j = blockIdx.x * 256 + threadIdx.x;
    if (j >= 256 * K) return;
    int n = j / K, k = j - n * K;
    float v = W[k * 256 + n];
    unsigned short h = f2bf(v);
    wth[j] = h;
    wtl[j] = f2bf(v - bf2f(h));
}

// ---------------- MFMA GEMM: H[M2,256] = A[M2,K] @ Bt[256,K]^T -> fp16 ----------------
// hi/lo split precision: C = Ah*Bh + Ah*Bl + Al*Bh  (f32 accumulate)

#define BK 64
#define SK 72   // padded LDS row stride (shorts)

__global__ __launch_bounds__(256, 2) void gemm_mfma_kernel(
        const unsigned short* __restrict__ Ah, const unsigned short* __restrict__ Al,
        const unsigned short* __restrict__ Bh, const unsigned short* __restrict__ Bl,
        _Float16* __restrict__ Hm, int K) {
    __shared__ unsigned short AsH[128 * SK], AsL[128 * SK];
    __shared__ unsigned short BsH[128 * SK], BsL[128 * SK];
    const int t = threadIdx.x;
    const int bn = blockIdx.x * 128;
    const int bm = blockIdx.y * 128;
    const int lane = t & 63, wv = t >> 6;
    const int wm = (wv >> 1) * 64, wn = (wv & 1) * 64;
    const int fr = lane & 15, q = lane >> 4;

    floatx4 acc[4][4] = {};

    const int lrow = t >> 3;          // 0..31
    const int lcol = (t & 7) * 8;     // 0..56

    for (int k0 = 0; k0 < K; k0 += BK) {
        for (int p = 0; p < 4; p++) {
            int row = p * 32 + lrow;
            size_t ga = (size_t)(bm + row) * K + k0 + lcol;
            size_t gb = (size_t)(bn + row) * K + k0 + lcol;
            *(short8*)&AsH[row * SK + lcol] = *(const short8*)&Ah[ga];
            *(short8*)&AsL[row * SK + lcol] = *(const short8*)&Al[ga];
            *(short8*)&BsH[row * SK + lcol] = *(const short8*)&Bh[gb];
            *(short8*)&BsL[row * SK + lcol] = *(const short8*)&Bl[gb];
        }
        __syncthreads();
        for (int kc = 0; kc < 2; kc++) {
            short8 ah[4], al[4], bh[4], bl[4];
            int ko = kc * 32 + q * 8;
            for (int mi = 0; mi < 4; mi++) {
                ah[mi] = *(const short8*)&AsH[(wm + mi * 16 + fr) * SK + ko];
                al[mi] = *(const short8*)&AsL[(wm + mi * 16 + fr) * SK + ko];
            }
            for (int ni = 0; ni < 4; ni++) {
                bh[ni] = *(const short8*)&BsH[(wn + ni * 16 + fr) * SK + ko];
                bl[ni] = *(const short8*)&BsL[(wn + ni * 16 + fr) * SK + ko];
            }
            for (int mi = 0; mi < 4; mi++)
                for (int ni = 0; ni < 4; ni++) {
                    acc[mi][ni] = __builtin_amdgcn_mfma_f32_16x16x32_bf16(
                        ah[mi], bh[ni], acc[mi][ni], 0, 0, 0);
                    acc[mi][ni] = __builtin_amdgcn_mfma_f32_16x16x32_bf16(
                        ah[mi], bl[ni], acc[mi][ni], 0, 0, 0);
                    acc[mi][ni] = __builtin_amdgcn_mfma_f32_16x16x32_bf16(
                        al[mi], bh[ni], acc[mi][ni], 0, 0, 0);
                }
        }
        __syncthreads();
    }
    // C/D layout: col = lane&15, row = (lane>>4)*4 + reg
    for (int mi = 0; mi < 4; mi++) {
        int row0 = bm + wm + mi * 16 + q * 4;
        for (int ni = 0; ni < 4; ni++) {
            int col = bn + wn + ni * 16 + fr;
            for (int r = 0; r < 4; r++)
                Hm[(size_t)(row0 + r) * CCH + col] = (_Float16)acc[mi][ni][r];
        }
    }
}

// ---------------- attention logits: alpha_src/dst [N,4] ----------------

__global__ __launch_bounds__(256) void alpha_kernel(const _Float16* __restrict__ H16,
                                                    const float* __restrict__ as_,
                                                    const float* __restrict__ ad_,
                                                    float* __restrict__ asrc,
                                                    float* __restrict__ adst) {
    int n = blockIdx.x, t = threadIdx.x;
    float h = (float)H16[(size_t)n * CCH + t];
    float ps = h * as_[t];
    float pd = h * ad_[t];
    for (int off = 32; off > 0; off >>= 1) {
        ps += __shfl_down(ps, off, 64);
        pd += __shfl_down(pd, off, 64);
    }
    if ((t & 63) == 0) {
        int hd = t >> 6;
        asrc[n * 4 + hd] = ps;
        adst[n * 4 + hd] = pd;
    }
}

// ---------------- softmax weights per (dst, head) ----------------

__global__ __launch_bounds__(256) void weight_kernel(const float* __restrict__ asrc,
                                                     const float* __restrict__ adst,
                                                     const int* __restrict__ rowptr,
                                                     const int* __restrict__ csrsrc,
                                                     float* __restrict__ w) {
    int i = blockIdx.x * 256 + threadIdx.x;   // over NND*4
    if (i >= NND * 4) return;
    int n = i >> 2, hd = i & 3;
    int rs = rowptr[n], re = rowptr[n + 1];
    float adv = adst[i];
    float m = -1e30f;
    for (int e = rs; e < re; e++) {
        int s = csrsrc[e];
        float ev = asrc[s * 4 + hd] + adv;
        ev = ev > 0.f ? ev : NEG * ev;
        w[e * 4 + hd] = ev;
        m = fmaxf(m, ev);
    }
    float ssum = 0.f;
    for (int e = rs; e < re; e++) {
        float v = __expf(w[e * 4 + hd] - m);
        w[e * 4 + hd] = v;
        ssum += v;
    }
    float inv = 1.f / ssum;
    for (int e = rs; e < re; e++) w[e * 4 + hd] *= inv;
}

// ---------------- weighted fp16 gather + bias + ELU -> bf16 hi/lo ----------------
// One wave per dst node; lane owns 4 channels. Edges in chunks of 16 with
// index/weight prefetched into registers and broadcast via shuffle.

__global__ __launch_bounds__(256) void agg_kernel(const _Float16* __restrict__ H16,
                                                  const float* __restrict__ w,
                                                  const int* __restrict__ rowptr,
                                                  const int* __restrict__ csrsrc,
                                                  const float4* __restrict__ bias4,
                                                  ushort4* __restrict__ xh4,
                                                  ushort4* __restrict__ xl4) {
    int wave = threadIdx.x >> 6, lane = threadIdx.x & 63;
    int n = blockIdx.x * 4 + wave;
    if (n >= NND) return;
    int rs = rowptr[n], re = rowptr[n + 1];
    int hd = lane >> 4;        // head of this lane's 4 channels
    int sub = lane & 15;
    float4 acc = make_float4(0.f, 0.f, 0.f, 0.f);
    for (int e0 = rs; e0 < re; e0 += 16) {
        int cnt = re - e0; if (cnt > 16) cnt = 16;
        int sl = e0 + sub;
        bool ok = sl < re;
        int idxv = ok ? csrsrc[sl] : 0;               // lanes hd*16+j hold edge e0+j's src
        float wv = ok ? w[sl * 4 + hd] : 0.f;         // lane hd*16+j holds w[(e0+j)*4+hd]
        for (int j = 0; j < cnt; j++) {
            int s = __shfl(idxv, j, 64);
            float ww = __shfl(wv, (lane & 48) | j, 64);
            half4 hv = *(const half4*)&H16[(size_t)s * CCH + lane * 4];
            acc.x += ww * (float)hv[0];
            acc.y += ww * (float)hv[1];
            acc.z += ww * (float)hv[2];
            acc.w += ww * (float)hv[3];
        }
    }
    float4 bv = bias4[lane];
    float4 o;
    o.x = acc.x + bv.x; o.y = acc.y + bv.y; o.z = acc.z + bv.z; o.w = acc.w + bv.w;
    o.x = o.x > 0.f ? o.x : expm1f(o.x);
    o.y = o.y > 0.f ? o.y : expm1f(o.y);
    o.z = o.z > 0.f ? o.z : expm1f(o.z);
    o.w = o.w > 0.f ? o.w : expm1f(o.w);
    ushort4 h, l;
    h.x = f2bf(o.x); l.x = f2bf(o.x - bf2f(h.x));
    h.y = f2bf(o.y); l.y = f2bf(o.y - bf2f(h.y));
    h.z = f2bf(o.z); l.z = f2bf(o.z - bf2f(h.z));
    h.w = f2bf(o.w); l.w = f2bf(o.w - bf2f(h.w));
    xh4[(size_t)n * 64 + lane] = h;
    xl4[(size_t)n * 64 + lane] = l;
}

// ---------------- pooling ----------------

__global__ void bounds_kernel(const int* __restrict__ batch, int* __restrict__ gstart) {
    int i = blockIdx.x * 256 + threadIdx.x;
    if (i >= NND) return;
    int b = batch[i];
    int bp = (i == 0) ? -1 : batch[i - 1];
    for (int g = bp + 1; g <= b; ++g) gstart[g] = i;
    if (i == NND - 1) {
        for (int g = b + 1; g <= NG; ++g) gstart[g] = NND;
    }
}

__global__ __launch_bounds__(256) void pool_kernel(const unsigned short* __restrict__ xh,
                                                   const unsigned short* __restrict__ xl,
                                                   const int* __restrict__ gstart,
                                                   float* __restrict__ gmean) {
    int g = blockIdx.x, t = threadIdx.x;
    int s = gstart[g], e = gstart[g + 1];
    float acc = 0.f;
    for (int i = s; i < e; i++)
        acc += bf2f(xh[(size_t)i * CCH + t]) + bf2f(xl[(size_t)i * CCH + t]);
    int cnt = e - s;
    gmean[g * CCH + t] = acc / (float)(cnt > 0 ? cnt : 1);
}

__global__ __launch_bounds__(128) void final_kernel(const float* __restrict__ gmean,
                                                    const float* __restrict__ Wf,
                                                    const float* __restrict__ bf,
                                                    float* __restrict__ out) {
    int g = blockIdx.x, c = threadIdx.x;
    const float* gv = gmean + g * CCH;
    float acc = bf[c];
    for (int k = 0; k < CCH; k++) acc += gv[k] * Wf[k * OUTD + c];
    __shared__ float red[128];
    red[c] = acc * acc;
    __syncthreads();
    for (int s = 64; s > 0; s >>= 1) {
        if (c < s) red[c] += red[c + s];
        __syncthreads();
    }
    float nrm = sqrtf(red[0]);
    out[g * OUTD + c] = acc / fmaxf(nrm, 1e-12f);
}

// ---------------- launch ----------------

extern "C" void kernel_launch(void* const* d_in, const int* in_sizes, int n_in,
                              void* d_out, int out_size, void* d_ws, size_t ws_size,
                              hipStream_t stream) {
    const float* x     = (const float*)d_in[0];
    const int*   ei    = (const int*)d_in[1];
    const int*   batch = (const int*)d_in[2];
    const float* W[3]  = {(const float*)d_in[3], (const float*)d_in[7],  (const float*)d_in[11]};
    const float* As[3] = {(const float*)d_in[4], (const float*)d_in[8],  (const float*)d_in[12]};
    const float* Ad[3] = {(const float*)d_in[5], (const float*)d_in[9],  (const float*)d_in[13]};
    const float* Bb[3] = {(const float*)d_in[6], (const float*)d_in[10], (const float*)d_in[14]};
    const float* Wf    = (const float*)d_in[15];
    const float* bf    = (const float*)d_in[16];
    float* out = (float*)d_out;

    // workspace layout
    _Float16* H16 = (_Float16*)d_ws;                              // M2*256 fp16
    unsigned short* xh  = (unsigned short*)(H16 + (size_t)M2 * CCH);   // M2*256 bf16
    unsigned short* xl  = xh + (size_t)M2 * CCH;
    unsigned short* wth = xl + (size_t)M2 * CCH;                  // 256*256
    unsigned short* wtl = wth + 256 * 256;
    float* asrc  = (float*)(wtl + 256 * 256);                     // NND*4
    float* adst  = asrc + (size_t)NND * 4;
    float* wbuf  = adst + (size_t)NND * 4;                        // ETOT*4
    float* gmean = wbuf + (size_t)ETOT * 4;                       // NG*256
    int* deg     = (int*)(gmean + (size_t)NG * CCH);              // NND+1
    int* rowptr  = deg + (NND + 1);
    int* cursor  = rowptr + (NND + 1);
    int* csrsrc  = cursor + (NND + 1);                            // ETOT
    int* gstart  = csrsrc + ETOT;                                 // NG+1
    int* bsum    = gstart + (NG + 1);                             // NBLK
    int* boff    = bsum + NBLK;
    int* total   = boff + NBLK;

    // CSR build (dst-indexed, with self-loops)
    zero_int_kernel<<<(NND + 1 + 255) / 256, 256, 0, stream>>>(deg, NND + 1);
    count_kernel<<<(ETOT + 255) / 256, 256, 0, stream>>>(ei, deg);
    scan_part_kernel<<<NBLK, 256, 0, stream>>>(deg, bsum);
    scan_bsum_kernel<<<1, 256, 0, stream>>>(bsum, boff, total);
    scan_write_kernel<<<NBLK, 256, 0, stream>>>(deg, boff, total, rowptr, cursor);
    scatter_kernel<<<(ETOT + 255) / 256, 256, 0, stream>>>(ei, cursor, csrsrc);
    bounds_kernel<<<(NND + 255) / 256, 256, 0, stream>>>(batch, gstart);

    // decompose layer-0 activations
    decomp_x_kernel<<<(NND * FEAT / 4 + 255) / 256, 256, 0, stream>>>(
        (const float4*)x, (ushort4*)xh, (ushort4*)xl);

    // 3 GAT layers
    int K = FEAT;
    for (int l = 0; l < 3; l++) {
        wdecomp_kernel<<<K, 256, 0, stream>>>(W[l], wth, wtl, K);
        dim3 g(2, M2 / 128);
        gemm_mfma_kernel<<<g, 256, 0, stream>>>(xh, xl, wth, wtl, H16, K);
        alpha_kernel<<<NND, 256, 0, stream>>>(H16, As[l], Ad[l], asrc, adst);
        weight_kernel<<<(NND * 4 + 255) / 256, 256, 0, stream>>>(asrc, adst, rowptr, csrsrc, wbuf);
        agg_kernel<<<(NND + 3) / 4, 256, 0, stream>>>(H16, wbuf, rowptr, csrsrc,
                                                      (const float4*)Bb[l], (ushort4*)xh, (ushort4*)xl);
        K = CCH;
    }

    // global mean pool + final linear + L2 normalize
    pool_kernel<<<NG, 256, 0, stream>>>(xh, xl, gstart, gmean);
    final_kernel<<<NG, 128, 0, stream>>>(gmean, Wf, bf, out);
}

// Round 6
// 635.689 us; speedup vs baseline: 2.9048x; 1.1940x over previous
//
#include <hip/hip_runtime.h>
#include <math.h>

#define NND 50000
#define NED 800000
#define ETOT 850000   // edges + self-loops
#define NG 256
#define FEAT 128
#define CCH 256       // HEADS*HID
#define OUTD 128
#define NEG 0.2f
#define NBLK 196      // ceil(NND/256)
#define M2 50048      // NND padded to 128

typedef __attribute__((ext_vector_type(8))) _Float16 half8;
typedef __attribute__((ext_vector_type(4))) _Float16 half4;
typedef __attribute__((ext_vector_type(4))) float floatx4;

// ---------------- CSR build ----------------

__global__ void zero_int_kernel(int* p, int n) {
    int i = blockIdx.x * 256 + threadIdx.x;
    if (i < n) p[i] = 0;
}

__global__ void count_kernel(const int* __restrict__ ei, int* __restrict__ deg) {
    int e = blockIdx.x * 256 + threadIdx.x;
    if (e >= ETOT) return;
    int dst = (e < NED) ? ei[NED + e] : (e - NED);
    atomicAdd(&deg[dst], 1);
}

__global__ __launch_bounds__(256) void scan_part_kernel(const int* __restrict__ deg,
                                                        int* __restrict__ bsum) {
    __shared__ int tile[256];
    int i = blockIdx.x * 256 + threadIdx.x;
    tile[threadIdx.x] = (i < NND) ? deg[i] : 0;
    __syncthreads();
    for (int s = 128; s > 0; s >>= 1) {
        if (threadIdx.x < s) tile[threadIdx.x] += tile[threadIdx.x + s];
        __syncthreads();
    }
    if (threadIdx.x == 0) bsum[blockIdx.x] = tile[0];
}

__global__ __launch_bounds__(256) void scan_bsum_kernel(int* __restrict__ bsum,
                                                        int* __restrict__ boff,
                                                        int* __restrict__ total) {
    __shared__ int tile[256];
    int t = threadIdx.x;
    int v = (t < NBLK) ? bsum[t] : 0;
    tile[t] = v;
    __syncthreads();
    for (int off = 1; off < 256; off <<= 1) {
        int u = (t >= off) ? tile[t - off] : 0;
        __syncthreads();
        tile[t] += u;
        __syncthreads();
    }
    if (t < NBLK) boff[t] = tile[t] - v;
    if (t == 255) *total = tile[255];
}

__global__ __launch_bounds__(256) void scan_write_kernel(const int* __restrict__ deg,
                                                         const int* __restrict__ boff,
                                                         const int* __restrict__ total,
                                                         int* __restrict__ rowptr,
                                                         int* __restrict__ cursor) {
    __shared__ int tile[256];
    int i = blockIdx.x * 256 + threadIdx.x;
    int t = threadIdx.x;
    int v = (i < NND) ? deg[i] : 0;
    tile[t] = v;
    __syncthreads();
    for (int off = 1; off < 256; off <<= 1) {
        int u = (t >= off) ? tile[t - off] : 0;
        __syncthreads();
        tile[t] += u;
        __syncthreads();
    }
    if (i < NND) {
        int r = boff[blockIdx.x] + tile[t] - v;
        rowptr[i] = r;
        cursor[i] = r;
    }
    if (i == 0) rowptr[NND] = *total;
}

__global__ void scatter_kernel(const int* __restrict__ ei, int* __restrict__ cursor,
                               int* __restrict__ csrsrc) {
    int e = blockIdx.x * 256 + threadIdx.x;
    if (e >= ETOT) return;
    int s, d;
    if (e < NED) { s = ei[e]; d = ei[NED + e]; } else { s = d = e - NED; }
    int pos = atomicAdd(&cursor[d], 1);
    csrsrc[pos] = s;
}

// ---------------- input conversion ----------------

// x [NND*128] f32 -> fp16 same layout
__global__ void decomp_x_kernel(const float4* __restrict__ x, half4* __restrict__ xo) {
    int i = blockIdx.x * 256 + threadIdx.x;
    if (i >= NND * FEAT / 4) return;
    float4 v = x[i];
    half4 o;
    o[0] = (_Float16)v.x; o[1] = (_Float16)v.y;
    o[2] = (_Float16)v.z; o[3] = (_Float16)v.w;
    xo[i] = o;
}

// W [K x 256] f32 -> Wt hi/lo [256 x K] fp16 (transposed, n-major)
__global__ void wdecomp_kernel(const float* __restrict__ W,
                               _Float16* __restrict__ wth,
                               _Float16* __restrict__ wtl, int K) {
    int j = blockIdx.x * 256 + threadIdx.x;
    if (j >= 256 * K) return;
    int n = j / K, k = j - n * K;
    float v = W[k * 256 + n];
    _Float16 h = (_Float16)v;
    wth[j] = h;
    wtl[j] = (_Float16)(v - (float)h);
}

// ---------------- MFMA GEMM: H[M2,256] = A[M2,K] @ Bt[256,K]^T -> fp16 ----------------
// A fp16; W fp16 hi/lo split: C = A*Bh + A*Bl  (f32 accumulate)

#define BK 64
#define SK 72   // padded LDS row stride (halves)

__global__ __launch_bounds__(256, 2) void gemm_mfma_kernel(
        const _Float16* __restrict__ A,
        const _Float16* __restrict__ Bh, const _Float16* __restrict__ Bl,
        _Float16* __restrict__ Hm, int K) {
    __shared__ _Float16 AsF[128 * SK];
    __shared__ _Float16 BsH[128 * SK], BsL[128 * SK];
    const int t = threadIdx.x;
    const int bn = blockIdx.x * 128;
    const int bm = blockIdx.y * 128;
    const int lane = t & 63, wv = t >> 6;
    const int wm = (wv >> 1) * 64, wn = (wv & 1) * 64;
    const int fr = lane & 15, q = lane >> 4;

    floatx4 acc[4][4] = {};

    const int lrow = t >> 3;          // 0..31
    const int lcol = (t & 7) * 8;     // 0..56

    for (int k0 = 0; k0 < K; k0 += BK) {
        for (int p = 0; p < 4; p++) {
            int row = p * 32 + lrow;
            size_t ga = (size_t)(bm + row) * K + k0 + lcol;
            size_t gb = (size_t)(bn + row) * K + k0 + lcol;
            *(half8*)&AsF[row * SK + lcol] = *(const half8*)&A[ga];
            *(half8*)&BsH[row * SK + lcol] = *(const half8*)&Bh[gb];
            *(half8*)&BsL[row * SK + lcol] = *(const half8*)&Bl[gb];
        }
        __syncthreads();
        for (int kc = 0; kc < 2; kc++) {
            half8 af[4], bh[4], bl[4];
            int ko = kc * 32 + q * 8;
            for (int mi = 0; mi < 4; mi++)
                af[mi] = *(const half8*)&AsF[(wm + mi * 16 + fr) * SK + ko];
            for (int ni = 0; ni < 4; ni++) {
                bh[ni] = *(const half8*)&BsH[(wn + ni * 16 + fr) * SK + ko];
                bl[ni] = *(const half8*)&BsL[(wn + ni * 16 + fr) * SK + ko];
            }
            for (int mi = 0; mi < 4; mi++)
                for (int ni = 0; ni < 4; ni++) {
                    acc[mi][ni] = __builtin_amdgcn_mfma_f32_16x16x32_f16(
                        af[mi], bh[ni], acc[mi][ni], 0, 0, 0);
                    acc[mi][ni] = __builtin_amdgcn_mfma_f32_16x16x32_f16(
                        af[mi], bl[ni], acc[mi][ni], 0, 0, 0);
                }
        }
        __syncthreads();
    }
    // C/D layout: col = lane&15, row = (lane>>4)*4 + reg
    for (int mi = 0; mi < 4; mi++) {
        int row0 = bm + wm + mi * 16 + q * 4;
        for (int ni = 0; ni < 4; ni++) {
            int col = bn + wn + ni * 16 + fr;
            for (int r = 0; r < 4; r++)
                Hm[(size_t)(row0 + r) * CCH + col] = (_Float16)acc[mi][ni][r];
        }
    }
}

// ---------------- attention logits: alpha_src/dst [N,4] ----------------

__global__ __launch_bounds__(256) void alpha_kernel(const _Float16* __restrict__ H16,
                                                    const float* __restrict__ as_,
                                                    const float* __restrict__ ad_,
                                                    float* __restrict__ asrc,
                                                    float* __restrict__ adst) {
    int n = blockIdx.x, t = threadIdx.x;
    float h = (float)H16[(size_t)n * CCH + t];
    float ps = h * as_[t];
    float pd = h * ad_[t];
    for (int off = 32; off > 0; off >>= 1) {
        ps += __shfl_down(ps, off, 64);
        pd += __shfl_down(pd, off, 64);
    }
    if ((t & 63) == 0) {
        int hd = t >> 6;
        asrc[n * 4 + hd] = ps;
        adst[n * 4 + hd] = pd;
    }
}

// ---------------- fused softmax + weighted fp16 gather + bias + ELU -> fp16 ----------------
// One wave per dst node; lane (hd,sub) computes exp-weight of edge e0+sub for
// head hd (no max subtraction: logits are O(1), f32 exp overflows at 88).
// Normalization by the shuffle-reduced sum happens once at the end.

__global__ __launch_bounds__(256) void agg_kernel(const _Float16* __restrict__ H16,
                                                  const float* __restrict__ asrc,
                                                  const float* __restrict__ adst,
                                                  const int* __restrict__ rowptr,
                                                  const int* __restrict__ csrsrc,
                                                  const float4* __restrict__ bias4,
                                                  half4* __restrict__ xo) {
    int wave = threadIdx.x >> 6, lane = threadIdx.x & 63;
    int n = blockIdx.x * 4 + wave;
    if (n >= NND) return;
    int rs = rowptr[n], re = rowptr[n + 1];
    int hd = lane >> 4;        // head of this lane's 4 channels
    int sub = lane & 15;
    float adv = adst[n * 4 + hd];
    float4 acc = make_float4(0.f, 0.f, 0.f, 0.f);
    float ssum = 0.f;
    for (int e0 = rs; e0 < re; e0 += 16) {
        int cnt = re - e0; if (cnt > 16) cnt = 16;
        int sl = e0 + sub;
        bool ok = sl < re;
        int idxv = ok ? csrsrc[sl] : 0;    // lane (hd,sub) holds edge e0+sub's src
        float ev = 0.f;
        if (ok) {
            float a = asrc[idxv * 4 + hd] + adv;   // asrc is L2-resident (800 KB)
            a = a > 0.f ? a : NEG * a;
            ev = __expf(a);
        }
        ssum += ev;
        for (int j = 0; j < cnt; j++) {
            int s = __shfl(idxv, j, 64);
            float ww = __shfl(ev, (lane & 48) | j, 64);
            half4 hv = *(const half4*)&H16[(size_t)s * CCH + lane * 4];
            acc.x += ww * (float)hv[0];
            acc.y += ww * (float)hv[1];
            acc.z += ww * (float)hv[2];
            acc.w += ww * (float)hv[3];
        }
    }
    // reduce ssum over the 16 sub-lanes of this head group
    for (int off = 1; off < 16; off <<= 1) ssum += __shfl_xor(ssum, off, 64);
    float inv = 1.f / ssum;
    float4 bv = bias4[lane];
    float4 o;
    o.x = acc.x * inv + bv.x; o.y = acc.y * inv + bv.y;
    o.z = acc.z * inv + bv.z; o.w = acc.w * inv + bv.w;
    o.x = o.x > 0.f ? o.x : expm1f(o.x);
    o.y = o.y > 0.f ? o.y : expm1f(o.y);
    o.z = o.z > 0.f ? o.z : expm1f(o.z);
    o.w = o.w > 0.f ? o.w : expm1f(o.w);
    half4 h;
    h[0] = (_Float16)o.x; h[1] = (_Float16)o.y;
    h[2] = (_Float16)o.z; h[3] = (_Float16)o.w;
    xo[(size_t)n * 64 + lane] = h;
}

// ---------------- pooling ----------------

__global__ void bounds_kernel(const int* __restrict__ batch, int* __restrict__ gstart) {
    int i = blockIdx.x * 256 + threadIdx.x;
    if (i >= NND) return;
    int b = batch[i];
    int bp = (i == 0) ? -1 : batch[i - 1];
    for (int g = bp + 1; g <= b; ++g) gstart[g] = i;
    if (i == NND - 1) {
        for (int g = b + 1; g <= NG; ++g) gstart[g] = NND;
    }
}

__global__ __launch_bounds__(256) void pool_kernel(const _Float16* __restrict__ xa,
                                                   const int* __restrict__ gstart,
                                                   float* __restrict__ gmean) {
    int g = blockIdx.x, t = threadIdx.x;
    int s = gstart[g], e = gstart[g + 1];
    float acc = 0.f;
    for (int i = s; i < e; i++)
        acc += (float)xa[(size_t)i * CCH + t];
    int cnt = e - s;
    gmean[g * CCH + t] = acc / (float)(cnt > 0 ? cnt : 1);
}

__global__ __launch_bounds__(128) void final_kernel(const float* __restrict__ gmean,
                                                    const float* __restrict__ Wf,
                                                    const float* __restrict__ bf,
                                                    float* __restrict__ out) {
    int g = blockIdx.x, c = threadIdx.x;
    const float* gv = gmean + g * CCH;
    float acc = bf[c];
    for (int k = 0; k < CCH; k++) acc += gv[k] * Wf[k * OUTD + c];
    __shared__ float red[128];
    red[c] = acc * acc;
    __syncthreads();
    for (int s = 64; s > 0; s >>= 1) {
        if (c < s) red[c] += red[c + s];
        __syncthreads();
    }
    float nrm = sqrtf(red[0]);
    out[g * OUTD + c] = acc / fmaxf(nrm, 1e-12f);
}

// ---------------- launch ----------------

extern "C" void kernel_launch(void* const* d_in, const int* in_sizes, int n_in,
                              void* d_out, int out_size, void* d_ws, size_t ws_size,
                              hipStream_t stream) {
    const float* x     = (const float*)d_in[0];
    const int*   ei    = (const int*)d_in[1];
    const int*   batch = (const int*)d_in[2];
    const float* W[3]  = {(const float*)d_in[3], (const float*)d_in[7],  (const float*)d_in[11]};
    const float* As[3] = {(const float*)d_in[4], (const float*)d_in[8],  (const float*)d_in[12]};
    const float* Ad[3] = {(const float*)d_in[5], (const float*)d_in[9],  (const float*)d_in[13]};
    const float* Bb[3] = {(const float*)d_in[6], (const float*)d_in[10], (const float*)d_in[14]};
    const float* Wf    = (const float*)d_in[15];
    const float* bf    = (const float*)d_in[16];
    float* out = (float*)d_out;

    // workspace layout
    _Float16* H16   = (_Float16*)d_ws;                            // M2*256 fp16 (gemm out / gather in)
    _Float16* act16 = H16 + (size_t)M2 * CCH;                     // M2*256 fp16 (agg out / gemm in)
    _Float16* wth   = act16 + (size_t)M2 * CCH;                   // 256*256
    _Float16* wtl   = wth + 256 * 256;
    float* asrc  = (float*)(wtl + 256 * 256);                     // NND*4
    float* adst  = asrc + (size_t)NND * 4;
    float* gmean = adst + (size_t)NND * 4;                        // NG*256
    int* deg     = (int*)(gmean + (size_t)NG * CCH);              // NND+1
    int* rowptr  = deg + (NND + 1);
    int* cursor  = rowptr + (NND + 1);
    int* csrsrc  = cursor + (NND + 1);                            // ETOT
    int* gstart  = csrsrc + ETOT;                                 // NG+1
    int* bsum    = gstart + (NG + 1);                             // NBLK
    int* boff    = bsum + NBLK;
    int* total   = boff + NBLK;

    // CSR build (dst-indexed, with self-loops)
    zero_int_kernel<<<(NND + 1 + 255) / 256, 256, 0, stream>>>(deg, NND + 1);
    count_kernel<<<(ETOT + 255) / 256, 256, 0, stream>>>(ei, deg);
    scan_part_kernel<<<NBLK, 256, 0, stream>>>(deg, bsum);
    scan_bsum_kernel<<<1, 256, 0, stream>>>(bsum, boff, total);
    scan_write_kernel<<<NBLK, 256, 0, stream>>>(deg, boff, total, rowptr, cursor);
    scatter_kernel<<<(ETOT + 255) / 256, 256, 0, stream>>>(ei, cursor, csrsrc);
    bounds_kernel<<<(NND + 255) / 256, 256, 0, stream>>>(batch, gstart);

    // layer-0 activations -> fp16
    decomp_x_kernel<<<(NND * FEAT / 4 + 255) / 256, 256, 0, stream>>>(
        (const float4*)x, (half4*)act16);

    // 3 GAT layers
    int K = FEAT;
    for (int l = 0; l < 3; l++) {
        wdecomp_kernel<<<K, 256, 0, stream>>>(W[l], wth, wtl, K);
        dim3 g(2, M2 / 128);
        gemm_mfma_kernel<<<g, 256, 0, stream>>>(act16, wth, wtl, H16, K);
        alpha_kernel<<<NND, 256, 0, stream>>>(H16, As[l], Ad[l], asrc, adst);
        agg_kernel<<<(NND + 3) / 4, 256, 0, stream>>>(H16, asrc, adst, rowptr, csrsrc,
                                                      (const float4*)Bb[l], (half4*)act16);
        K = CCH;
    }

    // global mean pool + final linear + L2 normalize
    pool_kernel<<<NG, 256, 0, stream>>>(act16, gstart, gmean);
    final_kernel<<<NG, 128, 0, stream>>>(gmean, Wf, bf, out);
}

// Round 7
// 559.983 us; speedup vs baseline: 3.2975x; 1.1352x over previous
//
#include <hip/hip_runtime.h>
#include <math.h>

#define NND 50000
#define NED 800000
#define ETOT 850000   // edges + self-loops
#define NG 256
#define FEAT 128
#define CCH 256       // HEADS*HID
#define OUTD 128
#define NEG 0.2f
#define NBLK 196      // ceil(NND/256)
#define M2 50048      // NND padded to 128

typedef __attribute__((ext_vector_type(8))) _Float16 half8;
typedef __attribute__((ext_vector_type(4))) _Float16 half4;
typedef __attribute__((ext_vector_type(4))) float floatx4;

// ---------------- CSR build ----------------

__global__ void zero_int_kernel(int* p, int n) {
    int i = blockIdx.x * 256 + threadIdx.x;
    if (i < n) p[i] = 0;
}

__global__ void count_kernel(const int* __restrict__ ei, int* __restrict__ deg) {
    int e = blockIdx.x * 256 + threadIdx.x;
    if (e >= ETOT) return;
    int dst = (e < NED) ? ei[NED + e] : (e - NED);
    atomicAdd(&deg[dst], 1);
}

__global__ __launch_bounds__(256) void scan_part_kernel(const int* __restrict__ deg,
                                                        int* __restrict__ bsum) {
    __shared__ int tile[256];
    int i = blockIdx.x * 256 + threadIdx.x;
    tile[threadIdx.x] = (i < NND) ? deg[i] : 0;
    __syncthreads();
    for (int s = 128; s > 0; s >>= 1) {
        if (threadIdx.x < s) tile[threadIdx.x] += tile[threadIdx.x + s];
        __syncthreads();
    }
    if (threadIdx.x == 0) bsum[blockIdx.x] = tile[0];
}

__global__ __launch_bounds__(256) void scan_bsum_kernel(int* __restrict__ bsum,
                                                        int* __restrict__ boff,
                                                        int* __restrict__ total) {
    __shared__ int tile[256];
    int t = threadIdx.x;
    int v = (t < NBLK) ? bsum[t] : 0;
    tile[t] = v;
    __syncthreads();
    for (int off = 1; off < 256; off <<= 1) {
        int u = (t >= off) ? tile[t - off] : 0;
        __syncthreads();
        tile[t] += u;
        __syncthreads();
    }
    if (t < NBLK) boff[t] = tile[t] - v;
    if (t == 255) *total = tile[255];
}

__global__ __launch_bounds__(256) void scan_write_kernel(const int* __restrict__ deg,
                                                         const int* __restrict__ boff,
                                                         const int* __restrict__ total,
                                                         int* __restrict__ rowptr,
                                                         int* __restrict__ cursor) {
    __shared__ int tile[256];
    int i = blockIdx.x * 256 + threadIdx.x;
    int t = threadIdx.x;
    int v = (i < NND) ? deg[i] : 0;
    tile[t] = v;
    __syncthreads();
    for (int off = 1; off < 256; off <<= 1) {
        int u = (t >= off) ? tile[t - off] : 0;
        __syncthreads();
        tile[t] += u;
        __syncthreads();
    }
    if (i < NND) {
        int r = boff[blockIdx.x] + tile[t] - v;
        rowptr[i] = r;
        cursor[i] = r;
    }
    if (i == 0) rowptr[NND] = *total;
}

__global__ void scatter_kernel(const int* __restrict__ ei, int* __restrict__ cursor,
                               int* __restrict__ csrsrc) {
    int e = blockIdx.x * 256 + threadIdx.x;
    if (e >= ETOT) return;
    int s, d;
    if (e < NED) { s = ei[e]; d = ei[NED + e]; } else { s = d = e - NED; }
    int pos = atomicAdd(&cursor[d], 1);
    csrsrc[pos] = s;
}

// ---------------- input conversion ----------------

// x [NND*128] f32 -> fp16 same layout
__global__ void decomp_x_kernel(const float4* __restrict__ x, half4* __restrict__ xo) {
    int i = blockIdx.x * 256 + threadIdx.x;
    if (i >= NND * FEAT / 4) return;
    float4 v = x[i];
    half4 o;
    o[0] = (_Float16)v.x; o[1] = (_Float16)v.y;
    o[2] = (_Float16)v.z; o[3] = (_Float16)v.w;
    xo[i] = o;
}

// W [K x 256] f32 -> Wt [256 x K] fp16 (transposed, n-major)
__global__ void wdecomp_kernel(const float* __restrict__ W,
                               _Float16* __restrict__ wt, int K) {
    int j = blockIdx.x * 256 + threadIdx.x;
    if (j >= 256 * K) return;
    int n = j / K, k = j - n * K;
    wt[j] = (_Float16)W[k * 256 + n];
}

// ---------------- MFMA GEMM + fused alpha epilogue ----------------
// H[M2,256] = A[M2,K] @ Wt[256,K]^T  (fp16 in, f32 acc, fp16 out)
// Each wave's 64 output cols == one head -> epilogue reduces
// ps/pd = sum(acc*a_s), sum(acc*a_d) over cols via shfl_xor and stores
// asrc/adst directly (each (row,head) produced by exactly one wave).

#define BK 64
#define SK 72   // padded LDS row stride (halves)

__global__ __launch_bounds__(256, 3) void gemm_mfma_kernel(
        const _Float16* __restrict__ A,
        const _Float16* __restrict__ Bt,
        const float* __restrict__ as_, const float* __restrict__ ad_,
        _Float16* __restrict__ Hm,
        float* __restrict__ asrc, float* __restrict__ adst, int K) {
    __shared__ _Float16 AsF[128 * SK];
    __shared__ _Float16 BsF[128 * SK];
    const int t = threadIdx.x;
    const int bn = blockIdx.x * 128;
    const int bm = blockIdx.y * 128;
    const int lane = t & 63, wv = t >> 6;
    const int wm = (wv >> 1) * 64, wn = (wv & 1) * 64;
    const int fr = lane & 15, q = lane >> 4;

    floatx4 acc[4][4] = {};

    const int lrow = t >> 3;          // 0..31
    const int lcol = (t & 7) * 8;     // 0..56

    for (int k0 = 0; k0 < K; k0 += BK) {
        for (int p = 0; p < 4; p++) {
            int row = p * 32 + lrow;
            size_t ga = (size_t)(bm + row) * K + k0 + lcol;
            size_t gb = (size_t)(bn + row) * K + k0 + lcol;
            *(half8*)&AsF[row * SK + lcol] = *(const half8*)&A[ga];
            *(half8*)&BsF[row * SK + lcol] = *(const half8*)&Bt[gb];
        }
        __syncthreads();
        for (int kc = 0; kc < 2; kc++) {
            half8 af[4], bf[4];
            int ko = kc * 32 + q * 8;
            for (int mi = 0; mi < 4; mi++)
                af[mi] = *(const half8*)&AsF[(wm + mi * 16 + fr) * SK + ko];
            for (int ni = 0; ni < 4; ni++)
                bf[ni] = *(const half8*)&BsF[(wn + ni * 16 + fr) * SK + ko];
            for (int mi = 0; mi < 4; mi++)
                for (int ni = 0; ni < 4; ni++)
                    acc[mi][ni] = __builtin_amdgcn_mfma_f32_16x16x32_f16(
                        af[mi], bf[ni], acc[mi][ni], 0, 0, 0);
        }
        __syncthreads();
    }

    // C/D layout: col = lane&15 (fr), row = q*4 + reg
    for (int mi = 0; mi < 4; mi++) {
        int row0 = bm + wm + mi * 16 + q * 4;
        for (int ni = 0; ni < 4; ni++) {
            int col = bn + wn + ni * 16 + fr;
            for (int r = 0; r < 4; r++)
                Hm[(size_t)(row0 + r) * CCH + col] = (_Float16)acc[mi][ni][r];
        }
    }

    // fused alpha: this wave's head
    const int hd = (bn + wn) >> 6;
    float asf[4], adf[4];
    for (int ni = 0; ni < 4; ni++) {
        asf[ni] = as_[hd * 64 + ni * 16 + fr];
        adf[ni] = ad_[hd * 64 + ni * 16 + fr];
    }
    for (int mi = 0; mi < 4; mi++)
        for (int r = 0; r < 4; r++) {
            float ps = 0.f, pd = 0.f;
            for (int ni = 0; ni < 4; ni++) {
                float v = acc[mi][ni][r];
                ps += v * asf[ni];
                pd += v * adf[ni];
            }
            for (int m = 1; m < 16; m <<= 1) {
                ps += __shfl_xor(ps, m, 64);
                pd += __shfl_xor(pd, m, 64);
            }
            if (fr == 0) {
                int row = bm + wm + mi * 16 + q * 4 + r;
                asrc[row * 4 + hd] = ps;
                adst[row * 4 + hd] = pd;
            }
        }
}

// ---------------- fused softmax + weighted fp16 gather + bias + ELU -> fp16 ----------------

__global__ __launch_bounds__(256) void agg_kernel(const _Float16* __restrict__ H16,
                                                  const float* __restrict__ asrc,
                                                  const float* __restrict__ adst,
                                                  const int* __restrict__ rowptr,
                                                  const int* __restrict__ csrsrc,
                                                  const float4* __restrict__ bias4,
                                                  half4* __restrict__ xo) {
    int wave = threadIdx.x >> 6, lane = threadIdx.x & 63;
    int n = blockIdx.x * 4 + wave;
    if (n >= NND) return;
    int rs = rowptr[n], re = rowptr[n + 1];
    int hd = lane >> 4;        // head of this lane's 4 channels
    int sub = lane & 15;
    float adv = adst[n * 4 + hd];
    float4 acc = make_float4(0.f, 0.f, 0.f, 0.f);
    float ssum = 0.f;
    for (int e0 = rs; e0 < re; e0 += 16) {
        int cnt = re - e0; if (cnt > 16) cnt = 16;
        int sl = e0 + sub;
        bool ok = sl < re;
        int idxv = ok ? csrsrc[sl] : 0;    // lane (hd,sub) holds edge e0+sub's src
        float ev = 0.f;
        if (ok) {
            float a = asrc[idxv * 4 + hd] + adv;   // asrc is L2-resident
            a = a > 0.f ? a : NEG * a;
            ev = __expf(a);
        }
        ssum += ev;
        for (int j = 0; j < cnt; j++) {
            int s = __shfl(idxv, j, 64);
            float ww = __shfl(ev, (lane & 48) | j, 64);
            half4 hv = *(const half4*)&H16[(size_t)s * CCH + lane * 4];
            acc.x += ww * (float)hv[0];
            acc.y += ww * (float)hv[1];
            acc.z += ww * (float)hv[2];
            acc.w += ww * (float)hv[3];
        }
    }
    for (int off = 1; off < 16; off <<= 1) ssum += __shfl_xor(ssum, off, 64);
    float inv = 1.f / ssum;
    float4 bv = bias4[lane];
    float4 o;
    o.x = acc.x * inv + bv.x; o.y = acc.y * inv + bv.y;
    o.z = acc.z * inv + bv.z; o.w = acc.w * inv + bv.w;
    o.x = o.x > 0.f ? o.x : expm1f(o.x);
    o.y = o.y > 0.f ? o.y : expm1f(o.y);
    o.z = o.z > 0.f ? o.z : expm1f(o.z);
    o.w = o.w > 0.f ? o.w : expm1f(o.w);
    half4 h;
    h[0] = (_Float16)o.x; h[1] = (_Float16)o.y;
    h[2] = (_Float16)o.z; h[3] = (_Float16)o.w;
    xo[(size_t)n * 64 + lane] = h;
}

// ---------------- pooling ----------------

__global__ void bounds_kernel(const int* __restrict__ batch, int* __restrict__ gstart) {
    int i = blockIdx.x * 256 + threadIdx.x;
    if (i >= NND) return;
    int b = batch[i];
    int bp = (i == 0) ? -1 : batch[i - 1];
    for (int g = bp + 1; g <= b; ++g) gstart[g] = i;
    if (i == NND - 1) {
        for (int g = b + 1; g <= NG; ++g) gstart[g] = NND;
    }
}

__global__ __launch_bounds__(256) void pool_kernel(const _Float16* __restrict__ xa,
                                                   const int* __restrict__ gstart,
                                                   float* __restrict__ gmean) {
    int g = blockIdx.x, t = threadIdx.x;
    int s = gstart[g], e = gstart[g + 1];
    float acc = 0.f;
    for (int i = s; i < e; i++)
        acc += (float)xa[(size_t)i * CCH + t];
    int cnt = e - s;
    gmean[g * CCH + t] = acc / (float)(cnt > 0 ? cnt : 1);
}

__global__ __launch_bounds__(128) void final_kernel(const float* __restrict__ gmean,
                                                    const float* __restrict__ Wf,
                                                    const float* __restrict__ bf,
                                                    float* __restrict__ out) {
    int g = blockIdx.x, c = threadIdx.x;
    const float* gv = gmean + g * CCH;
    float acc = bf[c];
    for (int k = 0; k < CCH; k++) acc += gv[k] * Wf[k * OUTD + c];
    __shared__ float red[128];
    red[c] = acc * acc;
    __syncthreads();
    for (int s = 64; s > 0; s >>= 1) {
        if (c < s) red[c] += red[c + s];
        __syncthreads();
    }
    float nrm = sqrtf(red[0]);
    out[g * OUTD + c] = acc / fmaxf(nrm, 1e-12f);
}

// ---------------- launch ----------------

extern "C" void kernel_launch(void* const* d_in, const int* in_sizes, int n_in,
                              void* d_out, int out_size, void* d_ws, size_t ws_size,
                              hipStream_t stream) {
    const float* x     = (const float*)d_in[0];
    const int*   ei    = (const int*)d_in[1];
    const int*   batch = (const int*)d_in[2];
    const float* W[3]  = {(const float*)d_in[3], (const float*)d_in[7],  (const float*)d_in[11]};
    const float* As[3] = {(const float*)d_in[4], (const float*)d_in[8],  (const float*)d_in[12]};
    const float* Ad[3] = {(const float*)d_in[5], (const float*)d_in[9],  (const float*)d_in[13]};
    const float* Bb[3] = {(const float*)d_in[6], (const float*)d_in[10], (const float*)d_in[14]};
    const float* Wf    = (const float*)d_in[15];
    const float* bf    = (const float*)d_in[16];
    float* out = (float*)d_out;

    // workspace layout
    _Float16* H16   = (_Float16*)d_ws;                            // M2*256 fp16 (gemm out / gather in)
    _Float16* act16 = H16 + (size_t)M2 * CCH;                     // M2*256 fp16 (agg out / gemm in)
    _Float16* wt    = act16 + (size_t)M2 * CCH;                   // 256*256
    float* asrc  = (float*)(wt + 256 * 256);                      // M2*4
    float* adst  = asrc + (size_t)M2 * 4;                         // M2*4
    float* gmean = adst + (size_t)M2 * 4;                         // NG*256
    int* deg     = (int*)(gmean + (size_t)NG * CCH);              // NND+1
    int* rowptr  = deg + (NND + 1);
    int* cursor  = rowptr + (NND + 1);
    int* csrsrc  = cursor + (NND + 1);                            // ETOT
    int* gstart  = csrsrc + ETOT;                                 // NG+1
    int* bsum    = gstart + (NG + 1);                             // NBLK
    int* boff    = bsum + NBLK;
    int* total   = boff + NBLK;

    // CSR build (dst-indexed, with self-loops)
    zero_int_kernel<<<(NND + 1 + 255) / 256, 256, 0, stream>>>(deg, NND + 1);
    count_kernel<<<(ETOT + 255) / 256, 256, 0, stream>>>(ei, deg);
    scan_part_kernel<<<NBLK, 256, 0, stream>>>(deg, bsum);
    scan_bsum_kernel<<<1, 256, 0, stream>>>(bsum, boff, total);
    scan_write_kernel<<<NBLK, 256, 0, stream>>>(deg, boff, total, rowptr, cursor);
    scatter_kernel<<<(ETOT + 255) / 256, 256, 0, stream>>>(ei, cursor, csrsrc);
    bounds_kernel<<<(NND + 255) / 256, 256, 0, stream>>>(batch, gstart);

    // layer-0 activations -> fp16
    decomp_x_kernel<<<(NND * FEAT / 4 + 255) / 256, 256, 0, stream>>>(
        (const float4*)x, (half4*)act16);

    // 3 GAT layers
    int K = FEAT;
    for (int l = 0; l < 3; l++) {
        wdecomp_kernel<<<K, 256, 0, stream>>>(W[l], wt, K);
        dim3 g(2, M2 / 128);
        gemm_mfma_kernel<<<g, 256, 0, stream>>>(act16, wt, As[l], Ad[l], H16, asrc, adst, K);
        agg_kernel<<<(NND + 3) / 4, 256, 0, stream>>>(H16, asrc, adst, rowptr, csrsrc,
                                                      (const float4*)Bb[l], (half4*)act16);
        K = CCH;
    }

    // global mean pool + final linear + L2 normalize
    pool_kernel<<<NG, 256, 0, stream>>>(act16, gstart, gmean);
    final_kernel<<<NG, 128, 0, stream>>>(gmean, Wf, bf, out);
}

// Round 8
// 551.726 us; speedup vs baseline: 3.3469x; 1.0150x over previous
//
#include <hip/hip_runtime.h>
#include <math.h>

#define NND 50000
#define NED 800000
#define ETOT 850000   // edges + self-loops
#define NG 256
#define FEAT 128
#define CCH 256       // HEADS*HID
#define OUTD 128
#define NEG 0.2f
#define NBLK 196      // ceil(NND/256)
#define M2 50048      // NND padded to 128

typedef __attribute__((ext_vector_type(8))) _Float16 half8;
typedef __attribute__((ext_vector_type(4))) _Float16 half4;
typedef __attribute__((ext_vector_type(4))) float floatx4;

#if __has_builtin(__builtin_amdgcn_global_load_lds)
#define GLOAD16(g, l) __builtin_amdgcn_global_load_lds( \
    (const __attribute__((address_space(1))) void*)(g), \
    (__attribute__((address_space(3))) void*)(l), 16, 0, 0)
#define HAVE_GLDS 1
#else
#define HAVE_GLDS 0
#endif

// ---------------- CSR build ----------------

__global__ void zero_int_kernel(int* p, int n) {
    int i = blockIdx.x * 256 + threadIdx.x;
    if (i < n) p[i] = 0;
}

__global__ void count_kernel(const int* __restrict__ ei, int* __restrict__ deg) {
    int e = blockIdx.x * 256 + threadIdx.x;
    if (e >= ETOT) return;
    int dst = (e < NED) ? ei[NED + e] : (e - NED);
    atomicAdd(&deg[dst], 1);
}

__global__ __launch_bounds__(256) void scan_part_kernel(const int* __restrict__ deg,
                                                        int* __restrict__ bsum) {
    __shared__ int tile[256];
    int i = blockIdx.x * 256 + threadIdx.x;
    tile[threadIdx.x] = (i < NND) ? deg[i] : 0;
    __syncthreads();
    for (int s = 128; s > 0; s >>= 1) {
        if (threadIdx.x < s) tile[threadIdx.x] += tile[threadIdx.x + s];
        __syncthreads();
    }
    if (threadIdx.x == 0) bsum[blockIdx.x] = tile[0];
}

__global__ __launch_bounds__(256) void scan_bsum_kernel(int* __restrict__ bsum,
                                                        int* __restrict__ boff,
                                                        int* __restrict__ total) {
    __shared__ int tile[256];
    int t = threadIdx.x;
    int v = (t < NBLK) ? bsum[t] : 0;
    tile[t] = v;
    __syncthreads();
    for (int off = 1; off < 256; off <<= 1) {
        int u = (t >= off) ? tile[t - off] : 0;
        __syncthreads();
        tile[t] += u;
        __syncthreads();
    }
    if (t < NBLK) boff[t] = tile[t] - v;
    if (t == 255) *total = tile[255];
}

__global__ __launch_bounds__(256) void scan_write_kernel(const int* __restrict__ deg,
                                                         const int* __restrict__ boff,
                                                         const int* __restrict__ total,
                                                         int* __restrict__ rowptr,
                                                         int* __restrict__ cursor) {
    __shared__ int tile[256];
    int i = blockIdx.x * 256 + threadIdx.x;
    int t = threadIdx.x;
    int v = (i < NND) ? deg[i] : 0;
    tile[t] = v;
    __syncthreads();
    for (int off = 1; off < 256; off <<= 1) {
        int u = (t >= off) ? tile[t - off] : 0;
        __syncthreads();
        tile[t] += u;
        __syncthreads();
    }
    if (i < NND) {
        int r = boff[blockIdx.x] + tile[t] - v;
        rowptr[i] = r;
        cursor[i] = r;
    }
    if (i == 0) rowptr[NND] = *total;
}

__global__ void scatter_kernel(const int* __restrict__ ei, int* __restrict__ cursor,
                               int* __restrict__ csrsrc) {
    int e = blockIdx.x * 256 + threadIdx.x;
    if (e >= ETOT) return;
    int s, d;
    if (e < NED) { s = ei[e]; d = ei[NED + e]; } else { s = d = e - NED; }
    int pos = atomicAdd(&cursor[d], 1);
    csrsrc[pos] = s;
}

// ---------------- input conversion ----------------

// x [NND*128] f32 -> fp16 same layout
__global__ void decomp_x_kernel(const float4* __restrict__ x, half4* __restrict__ xo) {
    int i = blockIdx.x * 256 + threadIdx.x;
    if (i >= NND * FEAT / 4) return;
    float4 v = x[i];
    half4 o;
    o[0] = (_Float16)v.x; o[1] = (_Float16)v.y;
    o[2] = (_Float16)v.z; o[3] = (_Float16)v.w;
    xo[i] = o;
}

// all three W [K x 256] f32 -> Wt [256 x K] fp16 (transposed) in one launch
__global__ void wdecomp_all_kernel(const float* __restrict__ W0,
                                   const float* __restrict__ W1,
                                   const float* __restrict__ W2,
                                   _Float16* __restrict__ wt0,
                                   _Float16* __restrict__ wt1,
                                   _Float16* __restrict__ wt2) {
    int j = blockIdx.x * 256 + threadIdx.x;
    if (j < 256 * 128) {
        int n = j >> 7, k = j & 127;
        wt0[j] = (_Float16)W0[k * 256 + n];
        return;
    }
    j -= 256 * 128;
    if (j < 256 * 256) {
        int n = j >> 8, k = j & 255;
        wt1[j] = (_Float16)W1[k * 256 + n];
        return;
    }
    j -= 256 * 256;
    if (j < 256 * 256) {
        int n = j >> 8, k = j & 255;
        wt2[j] = (_Float16)W2[k * 256 + n];
    }
}

// ---------------- MFMA GEMM + fused alpha epilogue ----------------
// H[M2,256] = A[M2,K] @ Wt[256,K]^T  (fp16 in, f32 acc, fp16 out)
// Staging via global_load_lds (16B/lane). LDS rows are unpadded (64 halves);
// bank conflicts avoided by XOR-swizzling WHICH 16B global block each lane
// fetches (LDS placement is forced lane-contiguous by the hardware), and
// XOR-ing the same term back on the fragment ds_reads.
// Epilogue: each wave's 64 cols == one head -> reduce ps/pd via shfl_xor,
// store asrc/adst directly.

#define BK 64

__global__ __launch_bounds__(256, 3) void gemm_mfma_kernel(
        const _Float16* __restrict__ A,
        const _Float16* __restrict__ Bt,
        const float* __restrict__ as_, const float* __restrict__ ad_,
        _Float16* __restrict__ Hm,
        float* __restrict__ asrc, float* __restrict__ adst, int K) {
    __shared__ _Float16 AsF[128 * 64];
    __shared__ _Float16 BsF[128 * 64];
    const int t = threadIdx.x;
    const int bn = blockIdx.x * 128;
    const int bm = blockIdx.y * 128;
    const int lane = t & 63, wv = t >> 6;
    const int wm = (wv >> 1) * 64, wn = (wv & 1) * 64;
    const int fr = lane & 15, q = lane >> 4;

    floatx4 acc[4][4] = {};

    const int lrow = t >> 3;          // 0..31
    const int c8 = t & 7;             // 16B block slot within LDS row

    for (int k0 = 0; k0 < K; k0 += BK) {
        for (int p = 0; p < 4; p++) {
            int row = p * 32 + lrow;
            int g8 = c8 ^ (row & 7);  // swizzled global block
            const _Float16* ga = A + (size_t)(bm + row) * K + k0 + g8 * 8;
            const _Float16* gb = Bt + (size_t)(bn + row) * K + k0 + g8 * 8;
#if HAVE_GLDS
            GLOAD16(ga, &AsF[row * 64 + c8 * 8]);
            GLOAD16(gb, &BsF[row * 64 + c8 * 8]);
#else
            *(half8*)&AsF[row * 64 + c8 * 8] = *(const half8*)ga;
            *(half8*)&BsF[row * 64 + c8 * 8] = *(const half8*)gb;
#endif
        }
        __syncthreads();
        for (int kc = 0; kc < 2; kc++) {
            half8 af[4], bf[4];
            int kb = kc * 4 + q;      // 16B k-block of this quad's fragment
            int cs = (kb ^ (fr & 7)) * 8;
            for (int mi = 0; mi < 4; mi++)
                af[mi] = *(const half8*)&AsF[(wm + mi * 16 + fr) * 64 + cs];
            for (int ni = 0; ni < 4; ni++)
                bf[ni] = *(const half8*)&BsF[(wn + ni * 16 + fr) * 64 + cs];
            for (int mi = 0; mi < 4; mi++)
                for (int ni = 0; ni < 4; ni++)
                    acc[mi][ni] = __builtin_amdgcn_mfma_f32_16x16x32_f16(
                        af[mi], bf[ni], acc[mi][ni], 0, 0, 0);
        }
        __syncthreads();
    }

    // C/D layout: col = lane&15 (fr), row = q*4 + reg
    for (int mi = 0; mi < 4; mi++) {
        int row0 = bm + wm + mi * 16 + q * 4;
        for (int ni = 0; ni < 4; ni++) {
            int col = bn + wn + ni * 16 + fr;
            for (int r = 0; r < 4; r++)
                Hm[(size_t)(row0 + r) * CCH + col] = (_Float16)acc[mi][ni][r];
        }
    }

    // fused alpha: this wave's head
    const int hd = (bn + wn) >> 6;
    float asf[4], adf[4];
    for (int ni = 0; ni < 4; ni++) {
        asf[ni] = as_[hd * 64 + ni * 16 + fr];
        adf[ni] = ad_[hd * 64 + ni * 16 + fr];
    }
    for (int mi = 0; mi < 4; mi++)
        for (int r = 0; r < 4; r++) {
            float ps = 0.f, pd = 0.f;
            for (int ni = 0; ni < 4; ni++) {
                float v = acc[mi][ni][r];
                ps += v * asf[ni];
                pd += v * adf[ni];
            }
            for (int m = 1; m < 16; m <<= 1) {
                ps += __shfl_xor(ps, m, 64);
                pd += __shfl_xor(pd, m, 64);
            }
            if (fr == 0) {
                int row = bm + wm + mi * 16 + q * 4 + r;
                asrc[row * 4 + hd] = ps;
                adst[row * 4 + hd] = pd;
            }
        }
}

// ---------------- fused softmax + weighted fp16 gather + bias + ELU -> fp16 ----------------

__global__ __launch_bounds__(256) void agg_kernel(const _Float16* __restrict__ H16,
                                                  const float* __restrict__ asrc,
                                                  const float* __restrict__ adst,
                                                  const int* __restrict__ rowptr,
                                                  const int* __restrict__ csrsrc,
                                                  const float4* __restrict__ bias4,
                                                  half4* __restrict__ xo) {
    int wave = threadIdx.x >> 6, lane = threadIdx.x & 63;
    int n = blockIdx.x * 4 + wave;
    if (n >= NND) return;
    int rs = rowptr[n], re = rowptr[n + 1];
    int hd = lane >> 4;        // head of this lane's 4 channels
    int sub = lane & 15;
    float adv = adst[n * 4 + hd];
    float4 acc = make_float4(0.f, 0.f, 0.f, 0.f);
    float ssum = 0.f;
    for (int e0 = rs; e0 < re; e0 += 16) {
        int cnt = re - e0; if (cnt > 16) cnt = 16;
        int sl = e0 + sub;
        bool ok = sl < re;
        int idxv = ok ? csrsrc[sl] : 0;    // lane (hd,sub) holds edge e0+sub's src
        float ev = 0.f;
        if (ok) {
            float a = asrc[idxv * 4 + hd] + adv;   // asrc is L2-resident
            a = a > 0.f ? a : NEG * a;
            ev = __expf(a);
        }
        ssum += ev;
        for (int j = 0; j < cnt; j++) {
            int s = __shfl(idxv, j, 64);
            float ww = __shfl(ev, (lane & 48) | j, 64);
            half4 hv = *(const half4*)&H16[(size_t)s * CCH + lane * 4];
            acc.x += ww * (float)hv[0];
            acc.y += ww * (float)hv[1];
            acc.z += ww * (float)hv[2];
            acc.w += ww * (float)hv[3];
        }
    }
    for (int off = 1; off < 16; off <<= 1) ssum += __shfl_xor(ssum, off, 64);
    float inv = 1.f / ssum;
    float4 bv = bias4[lane];
    float4 o;
    o.x = acc.x * inv + bv.x; o.y = acc.y * inv + bv.y;
    o.z = acc.z * inv + bv.z; o.w = acc.w * inv + bv.w;
    o.x = o.x > 0.f ? o.x : expm1f(o.x);
    o.y = o.y > 0.f ? o.y : expm1f(o.y);
    o.z = o.z > 0.f ? o.z : expm1f(o.z);
    o.w = o.w > 0.f ? o.w : expm1f(o.w);
    half4 h;
    h[0] = (_Float16)o.x; h[1] = (_Float16)o.y;
    h[2] = (_Float16)o.z; h[3] = (_Float16)o.w;
    xo[(size_t)n * 64 + lane] = h;
}

// ---------------- pooling + final linear + L2 norm (fused) ----------------

__global__ void bounds_kernel(const int* __restrict__ batch, int* __restrict__ gstart) {
    int i = blockIdx.x * 256 + threadIdx.x;
    if (i >= NND) return;
    int b = batch[i];
    int bp = (i == 0) ? -1 : batch[i - 1];
    for (int g = bp + 1; g <= b; ++g) gstart[g] = i;
    if (i == NND - 1) {
        for (int g = b + 1; g <= NG; ++g) gstart[g] = NND;
    }
}

__global__ __launch_bounds__(256) void poolfinal_kernel(const _Float16* __restrict__ xa,
                                                        const int* __restrict__ gstart,
                                                        const float* __restrict__ Wf,
                                                        const float* __restrict__ bfv,
                                                        float* __restrict__ out) {
    int g = blockIdx.x, t = threadIdx.x;
    __shared__ float gm[256];
    __shared__ float red[128];
    int s = gstart[g], e = gstart[g + 1];
    float acc = 0.f;
    for (int i = s; i < e; i++)
        acc += (float)xa[(size_t)i * CCH + t];
    int cnt = e - s;
    gm[t] = acc / (float)(cnt > 0 ? cnt : 1);
    __syncthreads();
    float a = 0.f;
    if (t < OUTD) {
        a = bfv[t];
        for (int k = 0; k < CCH; k++) a += gm[k] * Wf[k * OUTD + t];
        red[t] = a * a;
    }
    __syncthreads();
    for (int sft = 64; sft > 0; sft >>= 1) {
        if (t < sft) red[t] += red[t + sft];
        __syncthreads();
    }
    if (t < OUTD) out[g * OUTD + t] = a / fmaxf(sqrtf(red[0]), 1e-12f);
}

// ---------------- launch ----------------

extern "C" void kernel_launch(void* const* d_in, const int* in_sizes, int n_in,
                              void* d_out, int out_size, void* d_ws, size_t ws_size,
                              hipStream_t stream) {
    const float* x     = (const float*)d_in[0];
    const int*   ei    = (const int*)d_in[1];
    const int*   batch = (const int*)d_in[2];
    const float* W[3]  = {(const float*)d_in[3], (const float*)d_in[7],  (const float*)d_in[11]};
    const float* As[3] = {(const float*)d_in[4], (const float*)d_in[8],  (const float*)d_in[12]};
    const float* Ad[3] = {(const float*)d_in[5], (const float*)d_in[9],  (const float*)d_in[13]};
    const float* Bb[3] = {(const float*)d_in[6], (const float*)d_in[10], (const float*)d_in[14]};
    const float* Wf    = (const float*)d_in[15];
    const float* bf    = (const float*)d_in[16];
    float* out = (float*)d_out;

    // workspace layout
    _Float16* H16   = (_Float16*)d_ws;                            // M2*256 fp16 (gemm out / gather in)
    _Float16* act16 = H16 + (size_t)M2 * CCH;                     // M2*256 fp16 (agg out / gemm in)
    _Float16* wt0   = act16 + (size_t)M2 * CCH;                   // 256*128
    _Float16* wt1   = wt0 + 256 * 128;                            // 256*256
    _Float16* wt2   = wt1 + 256 * 256;                            // 256*256
    float* asrc  = (float*)(wt2 + 256 * 256);                     // M2*4
    float* adst  = asrc + (size_t)M2 * 4;                         // M2*4
    int* deg     = (int*)(adst + (size_t)M2 * 4);                 // NND+1
    int* rowptr  = deg + (NND + 1);
    int* cursor  = rowptr + (NND + 1);
    int* csrsrc  = cursor + (NND + 1);                            // ETOT
    int* gstart  = csrsrc + ETOT;                                 // NG+1
    int* bsum    = gstart + (NG + 1);                             // NBLK
    int* boff    = bsum + NBLK;
    int* total   = boff + NBLK;

    _Float16* wt[3] = {wt0, wt1, wt2};

    // CSR build (dst-indexed, with self-loops)
    zero_int_kernel<<<(NND + 1 + 255) / 256, 256, 0, stream>>>(deg, NND + 1);
    count_kernel<<<(ETOT + 255) / 256, 256, 0, stream>>>(ei, deg);
    scan_part_kernel<<<NBLK, 256, 0, stream>>>(deg, bsum);
    scan_bsum_kernel<<<1, 256, 0, stream>>>(bsum, boff, total);
    scan_write_kernel<<<NBLK, 256, 0, stream>>>(deg, boff, total, rowptr, cursor);
    scatter_kernel<<<(ETOT + 255) / 256, 256, 0, stream>>>(ei, cursor, csrsrc);
    bounds_kernel<<<(NND + 255) / 256, 256, 0, stream>>>(batch, gstart);

    // layer-0 activations -> fp16; all W -> fp16 transposed
    decomp_x_kernel<<<(NND * FEAT / 4 + 255) / 256, 256, 0, stream>>>(
        (const float4*)x, (half4*)act16);
    wdecomp_all_kernel<<<(256 * (128 + 256 + 256) + 255) / 256, 256, 0, stream>>>(
        W[0], W[1], W[2], wt0, wt1, wt2);

    // 3 GAT layers
    int K = FEAT;
    for (int l = 0; l < 3; l++) {
        dim3 g(2, M2 / 128);
        gemm_mfma_kernel<<<g, 256, 0, stream>>>(act16, wt[l], As[l], Ad[l], H16, asrc, adst, K);
        agg_kernel<<<(NND + 3) / 4, 256, 0, stream>>>(H16, asrc, adst, rowptr, csrsrc,
                                                      (const float4*)Bb[l], (half4*)act16);
        K = CCH;
    }

    // global mean pool + final linear + L2 normalize (fused)
    poolfinal_kernel<<<NG, 256, 0, stream>>>(act16, gstart, Wf, bf, out);
}